// Round 1
// baseline (589.888 us; speedup 1.0000x reference)
//
#include <hip/hip_runtime.h>
#include <math.h>

#define NB 8
#define SEQ 256
#define DIMC 512
#define NHEAD 8
#define DHEAD 64
#define SCALEF 0.125f

// ---------------- K1: LayerNorm (row = b*n), 2048 blocks x 256 ----------------
__global__ __launch_bounds__(256) void ln_kernel(const float* __restrict__ x,
    const float* __restrict__ g, const float* __restrict__ bta,
    float* __restrict__ xn) {
  const int row = blockIdx.x;
  const int t = threadIdx.x;
  const float2 v = ((const float2*)(x + (size_t)row * DIMC))[t];
  float s = v.x + v.y;
  float q = v.x * v.x + v.y * v.y;
#pragma unroll
  for (int off = 32; off > 0; off >>= 1) {
    s += __shfl_down(s, off);
    q += __shfl_down(q, off);
  }
  __shared__ float sh_s[4], sh_q[4];
  const int wave = t >> 6, lane = t & 63;
  if (lane == 0) { sh_s[wave] = s; sh_q[wave] = q; }
  __syncthreads();
  const float fs = sh_s[0] + sh_s[1] + sh_s[2] + sh_s[3];
  const float fq = sh_q[0] + sh_q[1] + sh_q[2] + sh_q[3];
  const float mean = fs * (1.0f / DIMC);
  const float inv = rsqrtf(fq * (1.0f / DIMC) - mean * mean + 1e-5f);
  const float2 gv = ((const float2*)g)[t];
  const float2 bv = ((const float2*)bta)[t];
  float2 o;
  o.x = (v.x - mean) * inv * gv.x + bv.x;
  o.y = (v.y - mean) * inv * gv.y + bv.y;
  ((float2*)(xn + (size_t)row * DIMC))[t] = o;
}

// ---------------- K2/K6: fp32 tiled GEMM, C = A(MxK) @ B(KxN) (+bias) -------
// 256 threads. Thread-tile TM x TN, block-tile BM x BN, BK=16.
template <int BM, int BN, int TM, int TN, bool BIAS>
__global__ __launch_bounds__(256) void gemm_kernel(const float* __restrict__ A,
    const float* __restrict__ Bw, const float* __restrict__ bias,
    float* __restrict__ C, int M, int K, int N) {
  __shared__ float As[16][BM + 4];  // [k][m] transposed
  __shared__ float Bs[16][BN];      // [k][n]
  const int t = threadIdx.x;
  const int NTX = BN / TN;  // 16
  const int tx = t % NTX;
  const int ty = t / NTX;
  const int bm = blockIdx.x, bn = blockIdx.y;
  float acc[TM][TN];
#pragma unroll
  for (int i = 0; i < TM; ++i)
#pragma unroll
    for (int j = 0; j < TN; ++j) acc[i][j] = 0.0f;

  const int ar = t >> 2;            // 0..63 row-in-tile base
  const int ak = (t & 3) * 4;       // k quad
  const int bc = (t % (BN / 4)) * 4;      // col quad
  const int bk0 = t / (BN / 4);           // k row base
  const int bks = 256 / (BN / 4);         // k row stride

  for (int kt = 0; kt < K; kt += 16) {
    float4 aR[BM / 64];
#pragma unroll
    for (int i = 0; i < BM / 64; ++i)
      aR[i] = *(const float4*)&A[(size_t)(bm * BM + ar + i * 64) * K + kt + ak];
    float4 bR[BN / 64];
#pragma unroll
    for (int i = 0; i < BN / 64; ++i)
      bR[i] = *(const float4*)&Bw[(size_t)(kt + bk0 + i * bks) * N + bn * BN + bc];
    __syncthreads();
#pragma unroll
    for (int i = 0; i < BM / 64; ++i) {
      As[ak + 0][ar + i * 64] = aR[i].x;
      As[ak + 1][ar + i * 64] = aR[i].y;
      As[ak + 2][ar + i * 64] = aR[i].z;
      As[ak + 3][ar + i * 64] = aR[i].w;
    }
#pragma unroll
    for (int i = 0; i < BN / 64; ++i)
      *(float4*)&Bs[bk0 + i * bks][bc] = bR[i];
    __syncthreads();
#pragma unroll
    for (int k = 0; k < 16; ++k) {
      float a[TM], bv[TN];
#pragma unroll
      for (int i = 0; i < TM; i += 4)
        *(float4*)&a[i] = *(const float4*)&As[k][ty * TM + i];
#pragma unroll
      for (int j = 0; j < TN; j += 4)
        *(float4*)&bv[j] = *(const float4*)&Bs[k][tx * TN + j];
#pragma unroll
      for (int i = 0; i < TM; ++i)
#pragma unroll
        for (int j = 0; j < TN; ++j) acc[i][j] += a[i] * bv[j];
    }
  }
#pragma unroll
  for (int i = 0; i < TM; ++i) {
    const int row = bm * BM + ty * TM + i;
#pragma unroll
    for (int j = 0; j < TN; j += 4) {
      const int col = bn * BN + tx * TN + j;
      float4 v;
      v.x = acc[i][j + 0] + (BIAS ? bias[col + 0] : 0.0f);
      v.y = acc[i][j + 1] + (BIAS ? bias[col + 1] : 0.0f);
      v.z = acc[i][j + 2] + (BIAS ? bias[col + 2] : 0.0f);
      v.w = acc[i][j + 3] + (BIAS ? bias[col + 3] : 0.0f);
      *(float4*)&C[(size_t)row * N + col] = v;
    }
  }
}

// ---------------- K3: QK^T * scale + softmax -> attn --------------------------
// grid (8 n-tiles of 32, 64 bh), 256 threads. Thread: 2 n-rows x 16 m-cols.
__global__ __launch_bounds__(256) void qk_softmax_kernel(
    const float* __restrict__ qkv, float* __restrict__ attn) {
  const int bh = blockIdx.y;
  const int b = bh >> 3, h = bh & 7;
  const int n0 = blockIdx.x * 32;
  const int t = threadIdx.x;
  const int tx = t & 15;   // m group (8 per chunk)
  const int ty = t >> 4;   // 0..15 -> 2 n rows
  __shared__ float qS[64][34];    // [d][n-local]
  __shared__ float kS[64][132];   // [d][m-local (chunk of 128)]
  // stage q^T
  {
    const int d = t & 63, w = t >> 6;
    for (int nn = w; nn < 32; nn += 4)
      qS[d][nn] = qkv[(size_t)(b * SEQ + n0 + nn) * 1536 + h * 64 + d];
  }
  float acc[2][16];
#pragma unroll
  for (int i = 0; i < 2; ++i)
#pragma unroll
    for (int j = 0; j < 16; ++j) acc[i][j] = 0.0f;

  for (int mc = 0; mc < 2; ++mc) {
    __syncthreads();
    {
      const int d = t & 63, w = t >> 6;
      for (int mm = w; mm < 128; mm += 4)
        kS[d][mm] = qkv[(size_t)(b * SEQ + mc * 128 + mm) * 1536 + 512 + h * 64 + d];
    }
    __syncthreads();
#pragma unroll 8
    for (int d = 0; d < 64; ++d) {
      const float2 q2 = *(const float2*)&qS[d][ty * 2];
      const float4 k0 = *(const float4*)&kS[d][tx * 8];
      const float4 k1 = *(const float4*)&kS[d][tx * 8 + 4];
      const int c = mc * 8;
      acc[0][c + 0] += q2.x * k0.x; acc[0][c + 1] += q2.x * k0.y;
      acc[0][c + 2] += q2.x * k0.z; acc[0][c + 3] += q2.x * k0.w;
      acc[0][c + 4] += q2.x * k1.x; acc[0][c + 5] += q2.x * k1.y;
      acc[0][c + 6] += q2.x * k1.z; acc[0][c + 7] += q2.x * k1.w;
      acc[1][c + 0] += q2.y * k0.x; acc[1][c + 1] += q2.y * k0.y;
      acc[1][c + 2] += q2.y * k0.z; acc[1][c + 3] += q2.y * k0.w;
      acc[1][c + 4] += q2.y * k1.x; acc[1][c + 5] += q2.y * k1.y;
      acc[1][c + 6] += q2.y * k1.z; acc[1][c + 7] += q2.y * k1.w;
    }
  }
  // softmax per row (row spread across the 16 tx lanes of the same ty)
#pragma unroll
  for (int i = 0; i < 2; ++i) {
    const int n = n0 + ty * 2 + i;
    float mx = -1e30f;
#pragma unroll
    for (int j = 0; j < 16; ++j) {
      acc[i][j] *= SCALEF;
      mx = fmaxf(mx, acc[i][j]);
    }
#pragma unroll
    for (int off = 1; off < 16; off <<= 1) mx = fmaxf(mx, __shfl_xor(mx, off));
    float sum = 0.0f;
#pragma unroll
    for (int j = 0; j < 16; ++j) {
      acc[i][j] = __expf(acc[i][j] - mx);
      sum += acc[i][j];
    }
#pragma unroll
    for (int off = 1; off < 16; off <<= 1) sum += __shfl_xor(sum, off);
    const float inv = 1.0f / sum;
    const size_t abase = (size_t)(bh * SEQ + n) * SEQ;
    float4 w;
    w.x = acc[i][0] * inv; w.y = acc[i][1] * inv; w.z = acc[i][2] * inv; w.w = acc[i][3] * inv;
    *(float4*)&attn[abase + tx * 8] = w;
    w.x = acc[i][4] * inv; w.y = acc[i][5] * inv; w.z = acc[i][6] * inv; w.w = acc[i][7] * inv;
    *(float4*)&attn[abase + tx * 8 + 4] = w;
    w.x = acc[i][8] * inv; w.y = acc[i][9] * inv; w.z = acc[i][10] * inv; w.w = acc[i][11] * inv;
    *(float4*)&attn[abase + 128 + tx * 8] = w;
    w.x = acc[i][12] * inv; w.y = acc[i][13] * inv; w.z = acc[i][14] * inv; w.w = acc[i][15] * inv;
    *(float4*)&attn[abase + 128 + tx * 8 + 4] = w;
  }
}

// ---------------- K4: relative-position term, writes o (init) ----------------
// grid 256 (n), 128 threads; thread owns c0..c0+3, all 8 b.
__global__ __launch_bounds__(128) void rpos_kernel(const float* __restrict__ attn,
    const float* __restrict__ up, const int* __restrict__ idxm,
    float* __restrict__ o) {
  const int n = blockIdx.x;
  const int t = threadIdx.x;
  const int c0 = t * 4;
  const int h = c0 >> 6;  // = t>>4
  __shared__ float aS[64 * 256];  // [bh][m ^ (h*4)] swizzled, 64 KB
#pragma unroll 4
  for (int i = 0; i < 32; ++i) {
    const int f4 = i * 128 + t;      // float4 index 0..4095
    const int bh = f4 >> 6;
    const int m4 = (f4 & 63) * 4;
    const float4 a = *(const float4*)&attn[(size_t)(bh * SEQ + n) * SEQ + m4];
    *(float4*)&aS[bh * 256 + (m4 ^ ((bh & 7) * 4))] = a;
  }
  __syncthreads();
  float acc[8][4];
#pragma unroll
  for (int b = 0; b < 8; ++b)
#pragma unroll
    for (int j = 0; j < 4; ++j) acc[b][j] = 0.0f;
  const int* idxr = idxm + n * SEQ;
  for (int mq = 0; mq < 64; ++mq) {
    const int4 rows = *(const int4*)&idxr[mq * 4];
    const float4 u0 = *(const float4*)&up[(size_t)rows.x * DIMC + c0];
    const float4 u1 = *(const float4*)&up[(size_t)rows.y * DIMC + c0];
    const float4 u2 = *(const float4*)&up[(size_t)rows.z * DIMC + c0];
    const float4 u3 = *(const float4*)&up[(size_t)rows.w * DIMC + c0];
    const int pbase = (mq * 4) ^ (h * 4);
#pragma unroll
    for (int b = 0; b < 8; ++b) {
      const float4 a = *(const float4*)&aS[(b * 8 + h) * 256 + pbase];
      acc[b][0] += a.x * u0.x + a.y * u1.x + a.z * u2.x + a.w * u3.x;
      acc[b][1] += a.x * u0.y + a.y * u1.y + a.z * u2.y + a.w * u3.y;
      acc[b][2] += a.x * u0.z + a.y * u1.z + a.z * u2.z + a.w * u3.z;
      acc[b][3] += a.x * u0.w + a.y * u1.w + a.z * u2.w + a.w * u3.w;
    }
  }
#pragma unroll
  for (int b = 0; b < 8; ++b)
    *(float4*)&o[(size_t)(b * SEQ + n) * DIMC + c0] = *(float4*)acc[b];
}

// ---------------- K5: attn @ V, atomicAdd into o ------------------------------
// grid (8 m-chunks of 32, 64 bh), 256 threads; thread: 8 n x 8 d.
__global__ __launch_bounds__(256) void av_kernel(const float* __restrict__ qkv,
    const float* __restrict__ attn, float* __restrict__ o) {
  const int bh = blockIdx.y;
  const int b = bh >> 3, h = bh & 7;
  const int m0 = blockIdx.x * 32;
  const int t = threadIdx.x;
  const int tx = t & 7;    // d-group
  const int ty = t >> 3;   // 0..31 n-group
  __shared__ float aS[32][264];  // [m-local][n]
  __shared__ float vS[32][68];   // [m-local][d]
  {
    const int mq = t & 7;
    for (int nn = t >> 3; nn < 256; nn += 32) {
      const float4 a4 =
          *(const float4*)&attn[(size_t)(bh * SEQ + nn) * SEQ + m0 + mq * 4];
      aS[mq * 4 + 0][nn] = a4.x;
      aS[mq * 4 + 1][nn] = a4.y;
      aS[mq * 4 + 2][nn] = a4.z;
      aS[mq * 4 + 3][nn] = a4.w;
    }
    const int d = t & 63;
    for (int mm = t >> 6; mm < 32; mm += 4)
      vS[mm][d] = qkv[(size_t)(b * SEQ + m0 + mm) * 1536 + 1024 + h * 64 + d];
  }
  __syncthreads();
  float acc[8][8];
#pragma unroll
  for (int i = 0; i < 8; ++i)
#pragma unroll
    for (int j = 0; j < 8; ++j) acc[i][j] = 0.0f;
#pragma unroll 4
  for (int m = 0; m < 32; ++m) {
    float a[8], v[8];
    *(float4*)&a[0] = *(const float4*)&aS[m][ty * 8];
    *(float4*)&a[4] = *(const float4*)&aS[m][ty * 8 + 4];
    *(float4*)&v[0] = *(const float4*)&vS[m][tx * 8];
    *(float4*)&v[4] = *(const float4*)&vS[m][tx * 8 + 4];
#pragma unroll
    for (int i = 0; i < 8; ++i)
#pragma unroll
      for (int j = 0; j < 8; ++j) acc[i][j] += a[i] * v[j];
  }
#pragma unroll
  for (int i = 0; i < 8; ++i) {
    const int n = ty * 8 + i;
    const size_t base = (size_t)(b * SEQ + n) * DIMC + h * 64 + tx * 8;
#pragma unroll
    for (int j = 0; j < 8; ++j) atomicAdd(&o[base + j], acc[i][j]);
  }
}

extern "C" void kernel_launch(void* const* d_in, const int* in_sizes, int n_in,
                              void* d_out, int out_size, void* d_ws,
                              size_t ws_size, hipStream_t stream) {
  const float* x = (const float*)d_in[0];
  const float* ln_g = (const float*)d_in[1];
  const float* ln_b = (const float*)d_in[2];
  const float* w_qkv = (const float*)d_in[3];
  const float* up = (const float*)d_in[4];
  const float* w_out = (const float*)d_in[5];
  const float* b_out = (const float*)d_in[6];
  const int* idxm = (const int*)d_in[7];
  float* out = (float*)d_out;

  float* ws = (float*)d_ws;
  float* xn = ws;                     // 2048*512   = 1,048,576
  float* qkv = ws + 1048576;          // 2048*1536  = 3,145,728
  float* attn = ws + 4194304;         // 64*256*256 = 4,194,304
  float* o = ws + 8388608;            // 2048*512   = 1,048,576
  if (ws_size < (size_t)9437184 * sizeof(float)) return;  // needs ~38 MB

  ln_kernel<<<2048, 256, 0, stream>>>(x, ln_g, ln_b, xn);
  gemm_kernel<128, 128, 8, 8, false>
      <<<dim3(16, 12), 256, 0, stream>>>(xn, w_qkv, nullptr, qkv, 2048, 512, 1536);
  qk_softmax_kernel<<<dim3(8, 64), 256, 0, stream>>>(qkv, attn);
  rpos_kernel<<<256, 128, 0, stream>>>(attn, up, idxm, o);
  av_kernel<<<dim3(8, 64), 256, 0, stream>>>(qkv, attn, o);
  gemm_kernel<128, 64, 8, 4, true>
      <<<dim3(16, 8), 256, 0, stream>>>(o, w_out, b_out, out, 2048, 512, 512);
}

// Round 2
// 279.600 us; speedup vs baseline: 2.1098x; 2.1098x over previous
//
#include <hip/hip_runtime.h>
#include <math.h>

#define NB 8
#define SEQ 256
#define DIMC 512
#define NHEAD 8
#define DHEAD 64
#define SCALEF 0.125f

// ---------------- K1: LayerNorm (row = b*n), 2048 blocks x 256 ----------------
__global__ __launch_bounds__(256) void ln_kernel(const float* __restrict__ x,
    const float* __restrict__ g, const float* __restrict__ bta,
    float* __restrict__ xn) {
  const int row = blockIdx.x;
  const int t = threadIdx.x;
  const float2 v = ((const float2*)(x + (size_t)row * DIMC))[t];
  float s = v.x + v.y;
  float q = v.x * v.x + v.y * v.y;
#pragma unroll
  for (int off = 32; off > 0; off >>= 1) {
    s += __shfl_down(s, off);
    q += __shfl_down(q, off);
  }
  __shared__ float sh_s[4], sh_q[4];
  const int wave = t >> 6, lane = t & 63;
  if (lane == 0) { sh_s[wave] = s; sh_q[wave] = q; }
  __syncthreads();
  const float fs = sh_s[0] + sh_s[1] + sh_s[2] + sh_s[3];
  const float fq = sh_q[0] + sh_q[1] + sh_q[2] + sh_q[3];
  const float mean = fs * (1.0f / DIMC);
  const float inv = rsqrtf(fq * (1.0f / DIMC) - mean * mean + 1e-5f);
  const float2 gv = ((const float2*)g)[t];
  const float2 bv = ((const float2*)bta)[t];
  float2 o;
  o.x = (v.x - mean) * inv * gv.x + bv.x;
  o.y = (v.y - mean) * inv * gv.y + bv.y;
  ((float2*)(xn + (size_t)row * DIMC))[t] = o;
}

// ---------------- K2/K6: fp32 tiled GEMM, C = A(MxK) @ B(KxN) (+bias) -------
// 256 threads. Thread-tile TM x TN, block-tile BM x BN, BK=16.
template <int BM, int BN, int TM, int TN, bool BIAS>
__global__ __launch_bounds__(256) void gemm_kernel(const float* __restrict__ A,
    const float* __restrict__ Bw, const float* __restrict__ bias,
    float* __restrict__ C, int M, int K, int N) {
  __shared__ float As[16][BM + 4];  // [k][m] transposed
  __shared__ float Bs[16][BN];      // [k][n]
  const int t = threadIdx.x;
  const int NTX = BN / TN;  // 16
  const int tx = t % NTX;
  const int ty = t / NTX;
  const int bm = blockIdx.x, bn = blockIdx.y;
  float acc[TM][TN];
#pragma unroll
  for (int i = 0; i < TM; ++i)
#pragma unroll
    for (int j = 0; j < TN; ++j) acc[i][j] = 0.0f;

  const int ar = t >> 2;            // 0..63 row-in-tile base
  const int ak = (t & 3) * 4;       // k quad
  const int bc = (t % (BN / 4)) * 4;      // col quad
  const int bk0 = t / (BN / 4);           // k row base
  const int bks = 256 / (BN / 4);         // k row stride

  for (int kt = 0; kt < K; kt += 16) {
    float4 aR[BM / 64];
#pragma unroll
    for (int i = 0; i < BM / 64; ++i)
      aR[i] = *(const float4*)&A[(size_t)(bm * BM + ar + i * 64) * K + kt + ak];
    float4 bR[BN / 64];
#pragma unroll
    for (int i = 0; i < BN / 64; ++i)
      bR[i] = *(const float4*)&Bw[(size_t)(kt + bk0 + i * bks) * N + bn * BN + bc];
    __syncthreads();
#pragma unroll
    for (int i = 0; i < BM / 64; ++i) {
      As[ak + 0][ar + i * 64] = aR[i].x;
      As[ak + 1][ar + i * 64] = aR[i].y;
      As[ak + 2][ar + i * 64] = aR[i].z;
      As[ak + 3][ar + i * 64] = aR[i].w;
    }
#pragma unroll
    for (int i = 0; i < BN / 64; ++i)
      *(float4*)&Bs[bk0 + i * bks][bc] = bR[i];
    __syncthreads();
#pragma unroll
    for (int k = 0; k < 16; ++k) {
      float a[TM], bv[TN];
#pragma unroll
      for (int i = 0; i < TM; i += 4)
        *(float4*)&a[i] = *(const float4*)&As[k][ty * TM + i];
#pragma unroll
      for (int j = 0; j < TN; j += 4)
        *(float4*)&bv[j] = *(const float4*)&Bs[k][tx * TN + j];
#pragma unroll
      for (int i = 0; i < TM; ++i)
#pragma unroll
        for (int j = 0; j < TN; ++j) acc[i][j] += a[i] * bv[j];
    }
  }
#pragma unroll
  for (int i = 0; i < TM; ++i) {
    const int row = bm * BM + ty * TM + i;
#pragma unroll
    for (int j = 0; j < TN; j += 4) {
      const int col = bn * BN + tx * TN + j;
      float4 v;
      v.x = acc[i][j + 0] + (BIAS ? bias[col + 0] : 0.0f);
      v.y = acc[i][j + 1] + (BIAS ? bias[col + 1] : 0.0f);
      v.z = acc[i][j + 2] + (BIAS ? bias[col + 2] : 0.0f);
      v.w = acc[i][j + 3] + (BIAS ? bias[col + 3] : 0.0f);
      *(float4*)&C[(size_t)row * N + col] = v;
    }
  }
}

// ---------------- K3: QK^T * scale + softmax -> attn --------------------------
// grid (8 n-tiles of 32, 64 bh), 256 threads. Thread: 2 n-rows x 16 m-cols.
__global__ __launch_bounds__(256) void qk_softmax_kernel(
    const float* __restrict__ qkv, float* __restrict__ attn) {
  const int bh = blockIdx.y;
  const int b = bh >> 3, h = bh & 7;
  const int n0 = blockIdx.x * 32;
  const int t = threadIdx.x;
  const int tx = t & 15;   // m group (8 per chunk)
  const int ty = t >> 4;   // 0..15 -> 2 n rows
  __shared__ float qS[64][34];    // [d][n-local]
  __shared__ float kS[64][132];   // [d][m-local (chunk of 128)]
  // stage q^T
  {
    const int d = t & 63, w = t >> 6;
    for (int nn = w; nn < 32; nn += 4)
      qS[d][nn] = qkv[(size_t)(b * SEQ + n0 + nn) * 1536 + h * 64 + d];
  }
  float acc[2][16];
#pragma unroll
  for (int i = 0; i < 2; ++i)
#pragma unroll
    for (int j = 0; j < 16; ++j) acc[i][j] = 0.0f;

  for (int mc = 0; mc < 2; ++mc) {
    __syncthreads();
    {
      const int d = t & 63, w = t >> 6;
      for (int mm = w; mm < 128; mm += 4)
        kS[d][mm] = qkv[(size_t)(b * SEQ + mc * 128 + mm) * 1536 + 512 + h * 64 + d];
    }
    __syncthreads();
#pragma unroll 8
    for (int d = 0; d < 64; ++d) {
      const float2 q2 = *(const float2*)&qS[d][ty * 2];
      const float4 k0 = *(const float4*)&kS[d][tx * 8];
      const float4 k1 = *(const float4*)&kS[d][tx * 8 + 4];
      const int c = mc * 8;
      acc[0][c + 0] += q2.x * k0.x; acc[0][c + 1] += q2.x * k0.y;
      acc[0][c + 2] += q2.x * k0.z; acc[0][c + 3] += q2.x * k0.w;
      acc[0][c + 4] += q2.x * k1.x; acc[0][c + 5] += q2.x * k1.y;
      acc[0][c + 6] += q2.x * k1.z; acc[0][c + 7] += q2.x * k1.w;
      acc[1][c + 0] += q2.y * k0.x; acc[1][c + 1] += q2.y * k0.y;
      acc[1][c + 2] += q2.y * k0.z; acc[1][c + 3] += q2.y * k0.w;
      acc[1][c + 4] += q2.y * k1.x; acc[1][c + 5] += q2.y * k1.y;
      acc[1][c + 6] += q2.y * k1.z; acc[1][c + 7] += q2.y * k1.w;
    }
  }
  // softmax per row (row spread across the 16 tx lanes of the same ty)
#pragma unroll
  for (int i = 0; i < 2; ++i) {
    const int n = n0 + ty * 2 + i;
    float mx = -1e30f;
#pragma unroll
    for (int j = 0; j < 16; ++j) {
      acc[i][j] *= SCALEF;
      mx = fmaxf(mx, acc[i][j]);
    }
#pragma unroll
    for (int off = 1; off < 16; off <<= 1) mx = fmaxf(mx, __shfl_xor(mx, off));
    float sum = 0.0f;
#pragma unroll
    for (int j = 0; j < 16; ++j) {
      acc[i][j] = __expf(acc[i][j] - mx);
      sum += acc[i][j];
    }
#pragma unroll
    for (int off = 1; off < 16; off <<= 1) sum += __shfl_xor(sum, off);
    const float inv = 1.0f / sum;
    const size_t abase = (size_t)(bh * SEQ + n) * SEQ;
    float4 w;
    w.x = acc[i][0] * inv; w.y = acc[i][1] * inv; w.z = acc[i][2] * inv; w.w = acc[i][3] * inv;
    *(float4*)&attn[abase + tx * 8] = w;
    w.x = acc[i][4] * inv; w.y = acc[i][5] * inv; w.z = acc[i][6] * inv; w.w = acc[i][7] * inv;
    *(float4*)&attn[abase + tx * 8 + 4] = w;
    w.x = acc[i][8] * inv; w.y = acc[i][9] * inv; w.z = acc[i][10] * inv; w.w = acc[i][11] * inv;
    *(float4*)&attn[abase + 128 + tx * 8] = w;
    w.x = acc[i][12] * inv; w.y = acc[i][13] * inv; w.z = acc[i][14] * inv; w.w = acc[i][15] * inv;
    *(float4*)&attn[abase + 128 + tx * 8 + 4] = w;
  }
}

// ---------------- K4: relative-position term, writes o (init) ----------------
// grid 256 (n), 128 threads; thread owns c0..c0+3, all 8 b.
__global__ __launch_bounds__(128) void rpos_kernel(const float* __restrict__ attn,
    const float* __restrict__ up, const int* __restrict__ idxm,
    float* __restrict__ o) {
  const int n = blockIdx.x;
  const int t = threadIdx.x;
  const int c0 = t * 4;
  const int h = c0 >> 6;  // = t>>4
  __shared__ float aS[64 * 256];  // [bh][m ^ (h*4)] swizzled, 64 KB
#pragma unroll 4
  for (int i = 0; i < 32; ++i) {
    const int f4 = i * 128 + t;      // float4 index 0..4095
    const int bh = f4 >> 6;
    const int m4 = (f4 & 63) * 4;
    const float4 a = *(const float4*)&attn[(size_t)(bh * SEQ + n) * SEQ + m4];
    *(float4*)&aS[bh * 256 + (m4 ^ ((bh & 7) * 4))] = a;
  }
  __syncthreads();
  float acc[8][4];
#pragma unroll
  for (int b = 0; b < 8; ++b)
#pragma unroll
    for (int j = 0; j < 4; ++j) acc[b][j] = 0.0f;
  const int* idxr = idxm + n * SEQ;
  for (int mq = 0; mq < 64; ++mq) {
    const int4 rows = *(const int4*)&idxr[mq * 4];
    const float4 u0 = *(const float4*)&up[(size_t)rows.x * DIMC + c0];
    const float4 u1 = *(const float4*)&up[(size_t)rows.y * DIMC + c0];
    const float4 u2 = *(const float4*)&up[(size_t)rows.z * DIMC + c0];
    const float4 u3 = *(const float4*)&up[(size_t)rows.w * DIMC + c0];
    const int pbase = (mq * 4) ^ (h * 4);
#pragma unroll
    for (int b = 0; b < 8; ++b) {
      const float4 a = *(const float4*)&aS[(b * 8 + h) * 256 + pbase];
      acc[b][0] += a.x * u0.x + a.y * u1.x + a.z * u2.x + a.w * u3.x;
      acc[b][1] += a.x * u0.y + a.y * u1.y + a.z * u2.y + a.w * u3.y;
      acc[b][2] += a.x * u0.z + a.y * u1.z + a.z * u2.z + a.w * u3.z;
      acc[b][3] += a.x * u0.w + a.y * u1.w + a.z * u2.w + a.w * u3.w;
    }
  }
#pragma unroll
  for (int b = 0; b < 8; ++b)
    *(float4*)&o[(size_t)(b * SEQ + n) * DIMC + c0] = *(float4*)acc[b];
}

// ---------------- K5: attn @ V, no atomics ------------------------------------
// grid (4 n-tiles of 64, 64 bh), 256 threads; block owns 64n x 64d for one bh,
// reduces over all 256 m in 8 chunks of 32. Epilogue: o += acc (each element
// owned by exactly one thread; rpos_kernel wrote o earlier in stream order).
__global__ __launch_bounds__(256) void av_kernel(const float* __restrict__ qkv,
    const float* __restrict__ attn, float* __restrict__ o) {
  const int bh = blockIdx.y;
  const int b = bh >> 3, h = bh & 7;
  const int n0 = blockIdx.x * 64;
  const int t = threadIdx.x;
  const int tx = t & 15;   // d-group: 16 x 4
  const int ty = t >> 4;   // n-group: 16 x 4
  __shared__ float aS[32][68];  // [m-local][n-local]
  __shared__ float vS[32][68];  // [m-local][d]
  float acc[4][4];
#pragma unroll
  for (int i = 0; i < 4; ++i)
#pragma unroll
    for (int j = 0; j < 4; ++j) acc[i][j] = 0.0f;

  // load-assignment constants
  const int a_nn = t >> 2;        // 0..63 row
  const int a_mq = (t & 3) * 8;   // 8 m per thread (2 float4)
  const int v_d4 = (t & 15) * 4;
  const int v_mm = t >> 4;        // 0..15 (+16 second half)

  for (int mc = 0; mc < 8; ++mc) {
    const int m0 = mc * 32;
    __syncthreads();
    {
      const float4 a0 = *(const float4*)&attn[(size_t)(bh * SEQ + n0 + a_nn) * SEQ + m0 + a_mq];
      const float4 a1 = *(const float4*)&attn[(size_t)(bh * SEQ + n0 + a_nn) * SEQ + m0 + a_mq + 4];
      aS[a_mq + 0][a_nn] = a0.x;
      aS[a_mq + 1][a_nn] = a0.y;
      aS[a_mq + 2][a_nn] = a0.z;
      aS[a_mq + 3][a_nn] = a0.w;
      aS[a_mq + 4][a_nn] = a1.x;
      aS[a_mq + 5][a_nn] = a1.y;
      aS[a_mq + 6][a_nn] = a1.z;
      aS[a_mq + 7][a_nn] = a1.w;
      *(float4*)&vS[v_mm][v_d4] =
          *(const float4*)&qkv[(size_t)(b * SEQ + m0 + v_mm) * 1536 + 1024 + h * 64 + v_d4];
      *(float4*)&vS[v_mm + 16][v_d4] =
          *(const float4*)&qkv[(size_t)(b * SEQ + m0 + v_mm + 16) * 1536 + 1024 + h * 64 + v_d4];
    }
    __syncthreads();
#pragma unroll 8
    for (int m = 0; m < 32; ++m) {
      float a[4], v[4];
      *(float4*)&a[0] = *(const float4*)&aS[m][ty * 4];
      *(float4*)&v[0] = *(const float4*)&vS[m][tx * 4];
#pragma unroll
      for (int i = 0; i < 4; ++i)
#pragma unroll
        for (int j = 0; j < 4; ++j) acc[i][j] += a[i] * v[j];
    }
  }
#pragma unroll
  for (int i = 0; i < 4; ++i) {
    const int n = n0 + ty * 4 + i;
    const size_t base = (size_t)(b * SEQ + n) * DIMC + h * 64 + tx * 4;
    float4 ov = *(float4*)&o[base];
    ov.x += acc[i][0];
    ov.y += acc[i][1];
    ov.z += acc[i][2];
    ov.w += acc[i][3];
    *(float4*)&o[base] = ov;
  }
}

extern "C" void kernel_launch(void* const* d_in, const int* in_sizes, int n_in,
                              void* d_out, int out_size, void* d_ws,
                              size_t ws_size, hipStream_t stream) {
  const float* x = (const float*)d_in[0];
  const float* ln_g = (const float*)d_in[1];
  const float* ln_b = (const float*)d_in[2];
  const float* w_qkv = (const float*)d_in[3];
  const float* up = (const float*)d_in[4];
  const float* w_out = (const float*)d_in[5];
  const float* b_out = (const float*)d_in[6];
  const int* idxm = (const int*)d_in[7];
  float* out = (float*)d_out;

  float* ws = (float*)d_ws;
  float* xn = ws;                     // 2048*512   = 1,048,576
  float* qkv = ws + 1048576;          // 2048*1536  = 3,145,728
  float* attn = ws + 4194304;         // 64*256*256 = 4,194,304
  float* o = ws + 8388608;            // 2048*512   = 1,048,576
  if (ws_size < (size_t)9437184 * sizeof(float)) return;  // needs ~38 MB

  ln_kernel<<<2048, 256, 0, stream>>>(x, ln_g, ln_b, xn);
  gemm_kernel<128, 128, 8, 8, false>
      <<<dim3(16, 12), 256, 0, stream>>>(xn, w_qkv, nullptr, qkv, 2048, 512, 1536);
  qk_softmax_kernel<<<dim3(8, 64), 256, 0, stream>>>(qkv, attn);
  rpos_kernel<<<256, 128, 0, stream>>>(attn, up, idxm, o);
  av_kernel<<<dim3(4, 64), 256, 0, stream>>>(qkv, attn, o);
  gemm_kernel<128, 64, 8, 4, true>
      <<<dim3(16, 8), 256, 0, stream>>>(o, w_out, b_out, out, 2048, 512, 512);
}

// Round 3
// 183.007 us; speedup vs baseline: 3.2233x; 1.5278x over previous
//
#include <hip/hip_runtime.h>
#include <math.h>

#define NB 8
#define SEQ 256
#define DIMC 512
#define NHEAD 8
#define DHEAD 64
#define SCALEF 0.125f

typedef __attribute__((ext_vector_type(8))) short s16x8;
typedef __attribute__((ext_vector_type(4))) float f32x4;

static __device__ __forceinline__ unsigned short f2bf(float f) {
  union { float f; unsigned u; } c; c.f = f;
  unsigned r = c.u + 0x7FFF + ((c.u >> 16) & 1);  // RNE
  return (unsigned short)(r >> 16);
}
static __device__ __forceinline__ float bf2f(unsigned short u) {
  union { unsigned u; float f; } c; c.u = ((unsigned)u) << 16;
  return c.f;
}

// ---------------- K0: transpose + cast fp32 W(KxN) -> bf16 WT(NxK) -----------
__global__ __launch_bounds__(256) void tcast_kernel(const float* __restrict__ W,
    unsigned short* __restrict__ WT, int K, int N) {
  const int n0 = blockIdx.x * 64, k0 = blockIdx.y * 64;
  __shared__ float tile[64][65];
  const int t = threadIdx.x;
#pragma unroll
  for (int i = 0; i < 16; ++i) {
    const int idx = i * 256 + t;
    const int kl = idx >> 6, nl = idx & 63;
    tile[kl][nl] = W[(size_t)(k0 + kl) * N + n0 + nl];
  }
  __syncthreads();
#pragma unroll
  for (int i = 0; i < 16; ++i) {
    const int idx = i * 256 + t;
    const int nl = idx >> 6, kl = idx & 63;
    WT[(size_t)(n0 + nl) * K + k0 + kl] = f2bf(tile[kl][nl]);
  }
}

// ---------------- K1: LayerNorm -> bf16 xn, 2048 blocks x 256 ----------------
__global__ __launch_bounds__(256) void ln_kernel(const float* __restrict__ x,
    const float* __restrict__ g, const float* __restrict__ bta,
    unsigned short* __restrict__ xnb) {
  const int row = blockIdx.x;
  const int t = threadIdx.x;
  const float2 v = ((const float2*)(x + (size_t)row * DIMC))[t];
  float s = v.x + v.y;
  float q = v.x * v.x + v.y * v.y;
#pragma unroll
  for (int off = 32; off > 0; off >>= 1) {
    s += __shfl_down(s, off);
    q += __shfl_down(q, off);
  }
  __shared__ float sh_s[4], sh_q[4];
  const int wave = t >> 6, lane = t & 63;
  if (lane == 0) { sh_s[wave] = s; sh_q[wave] = q; }
  __syncthreads();
  const float fs = sh_s[0] + sh_s[1] + sh_s[2] + sh_s[3];
  const float fq = sh_q[0] + sh_q[1] + sh_q[2] + sh_q[3];
  const float mean = fs * (1.0f / DIMC);
  const float inv = rsqrtf(fq * (1.0f / DIMC) - mean * mean + 1e-5f);
  const float2 gv = ((const float2*)g)[t];
  const float2 bv = ((const float2*)bta)[t];
  ushort2 o;
  o.x = f2bf((v.x - mean) * inv * gv.x + bv.x);
  o.y = f2bf((v.y - mean) * inv * gv.y + bv.y);
  ((ushort2*)(xnb + (size_t)row * DIMC))[t] = o;
}

// ---------------- bf16 MFMA GEMM: C(MxN) = A(MxK) @ BT(NxK)^T (+bias) --------
// 256 threads = 4 waves; wave (wr,wc) owns (BM/2)x(BN/2); 16x16x32 MFMA tiles.
template <int BM, int BN, bool BIAS>
__global__ __launch_bounds__(256) void mfma_gemm_bt(
    const unsigned short* __restrict__ A, const unsigned short* __restrict__ BT,
    const float* __restrict__ bias, float* __restrict__ C,
    int M, int K, int N) {
  constexpr int TR = BM / 32;  // MFMA row-tiles per wave
  constexpr int TC = BN / 32;  // MFMA col-tiles per wave
  __shared__ unsigned short As[BM * 32];
  __shared__ unsigned short Bs[BN * 32];
  const int t = threadIdx.x;
  const int wave = t >> 6, lane = t & 63;
  const int wr = wave >> 1, wc = wave & 1;
  const int bm = blockIdx.x * BM, bn = blockIdx.y * BN;

  f32x4 acc[TR][TC] = {};

  const int fr = lane & 15, q = lane >> 4;  // frag row, k-quad
  const int kBlocks = K >> 5;
  for (int kb = 0; kb < kBlocks; ++kb) {
    const int k0 = kb << 5;
    __syncthreads();
    // stage A tile (BM x 32) and B tile (BN x 32), 16B chunks
#pragma unroll
    for (int c = 0; c < BM * 4 / 256; ++c) {
      const int chunk = c * 256 + t;
      const int row = chunk >> 2, j = chunk & 3;
      const s16x8 v = *(const s16x8*)(A + (size_t)(bm + row) * K + k0 + j * 8);
      *(s16x8*)(As + row * 32 + j * 8) = v;
    }
#pragma unroll
    for (int c = 0; c < BN * 4 / 256; ++c) {
      const int chunk = c * 256 + t;
      const int row = chunk >> 2, j = chunk & 3;
      const s16x8 v = *(const s16x8*)(BT + (size_t)(bn + row) * K + k0 + j * 8);
      *(s16x8*)(Bs + row * 32 + j * 8) = v;
    }
    __syncthreads();
    s16x8 af[TR], bfr[TC];
#pragma unroll
    for (int i = 0; i < TR; ++i) {
      const int row = wr * (BM / 2) + i * 16 + fr;
      af[i] = *(const s16x8*)(As + row * 32 + q * 8);
    }
#pragma unroll
    for (int j = 0; j < TC; ++j) {
      const int row = wc * (BN / 2) + j * 16 + fr;
      bfr[j] = *(const s16x8*)(Bs + row * 32 + q * 8);
    }
#pragma unroll
    for (int i = 0; i < TR; ++i)
#pragma unroll
      for (int j = 0; j < TC; ++j)
        acc[i][j] = __builtin_amdgcn_mfma_f32_16x16x32_bf16(af[i], bfr[j],
                                                            acc[i][j], 0, 0, 0);
  }
  // epilogue: C/D layout col=lane&15, row=(lane>>4)*4+reg
#pragma unroll
  for (int i = 0; i < TR; ++i) {
#pragma unroll
    for (int j = 0; j < TC; ++j) {
      const int col = bn + wc * (BN / 2) + j * 16 + fr;
      const float bv = BIAS ? bias[col] : 0.0f;
#pragma unroll
      for (int r = 0; r < 4; ++r) {
        const int row = bm + wr * (BM / 2) + i * 16 + q * 4 + r;
        C[(size_t)row * N + col] = acc[i][j][r] + bv;
      }
    }
  }
}

// ---------------- K3: QK^T * scale + softmax -> attn (fp32) ------------------
__global__ __launch_bounds__(256) void qk_softmax_kernel(
    const float* __restrict__ qkv, float* __restrict__ attn) {
  const int bh = blockIdx.y;
  const int b = bh >> 3, h = bh & 7;
  const int n0 = blockIdx.x * 32;
  const int t = threadIdx.x;
  const int tx = t & 15;
  const int ty = t >> 4;
  __shared__ float qS[64][34];
  __shared__ float kS[64][132];
  {
    const int d = t & 63, w = t >> 6;
    for (int nn = w; nn < 32; nn += 4)
      qS[d][nn] = qkv[(size_t)(b * SEQ + n0 + nn) * 1536 + h * 64 + d];
  }
  float acc[2][16];
#pragma unroll
  for (int i = 0; i < 2; ++i)
#pragma unroll
    for (int j = 0; j < 16; ++j) acc[i][j] = 0.0f;

  for (int mc = 0; mc < 2; ++mc) {
    __syncthreads();
    {
      const int d = t & 63, w = t >> 6;
      for (int mm = w; mm < 128; mm += 4)
        kS[d][mm] = qkv[(size_t)(b * SEQ + mc * 128 + mm) * 1536 + 512 + h * 64 + d];
    }
    __syncthreads();
#pragma unroll 8
    for (int d = 0; d < 64; ++d) {
      const float2 q2 = *(const float2*)&qS[d][ty * 2];
      const float4 k0 = *(const float4*)&kS[d][tx * 8];
      const float4 k1 = *(const float4*)&kS[d][tx * 8 + 4];
      const int c = mc * 8;
      acc[0][c + 0] += q2.x * k0.x; acc[0][c + 1] += q2.x * k0.y;
      acc[0][c + 2] += q2.x * k0.z; acc[0][c + 3] += q2.x * k0.w;
      acc[0][c + 4] += q2.x * k1.x; acc[0][c + 5] += q2.x * k1.y;
      acc[0][c + 6] += q2.x * k1.z; acc[0][c + 7] += q2.x * k1.w;
      acc[1][c + 0] += q2.y * k0.x; acc[1][c + 1] += q2.y * k0.y;
      acc[1][c + 2] += q2.y * k0.z; acc[1][c + 3] += q2.y * k0.w;
      acc[1][c + 4] += q2.y * k1.x; acc[1][c + 5] += q2.y * k1.y;
      acc[1][c + 6] += q2.y * k1.z; acc[1][c + 7] += q2.y * k1.w;
    }
  }
#pragma unroll
  for (int i = 0; i < 2; ++i) {
    const int n = n0 + ty * 2 + i;
    float mx = -1e30f;
#pragma unroll
    for (int j = 0; j < 16; ++j) {
      acc[i][j] *= SCALEF;
      mx = fmaxf(mx, acc[i][j]);
    }
#pragma unroll
    for (int off = 1; off < 16; off <<= 1) mx = fmaxf(mx, __shfl_xor(mx, off));
    float sum = 0.0f;
#pragma unroll
    for (int j = 0; j < 16; ++j) {
      acc[i][j] = __expf(acc[i][j] - mx);
      sum += acc[i][j];
    }
#pragma unroll
    for (int off = 1; off < 16; off <<= 1) sum += __shfl_xor(sum, off);
    const float inv = 1.0f / sum;
    const size_t abase = (size_t)(bh * SEQ + n) * SEQ;
    float4 w;
    w.x = acc[i][0] * inv; w.y = acc[i][1] * inv; w.z = acc[i][2] * inv; w.w = acc[i][3] * inv;
    *(float4*)&attn[abase + tx * 8] = w;
    w.x = acc[i][4] * inv; w.y = acc[i][5] * inv; w.z = acc[i][6] * inv; w.w = acc[i][7] * inv;
    *(float4*)&attn[abase + tx * 8 + 4] = w;
    w.x = acc[i][8] * inv; w.y = acc[i][9] * inv; w.z = acc[i][10] * inv; w.w = acc[i][11] * inv;
    *(float4*)&attn[abase + 128 + tx * 8] = w;
    w.x = acc[i][12] * inv; w.y = acc[i][13] * inv; w.z = acc[i][14] * inv; w.w = acc[i][15] * inv;
    *(float4*)&attn[abase + 128 + tx * 8 + 4] = w;
  }
}

// ---------------- K4: relative-position term -> o (bf16, init) ---------------
__global__ __launch_bounds__(128) void rpos_kernel(const float* __restrict__ attn,
    const float* __restrict__ up, const int* __restrict__ idxm,
    unsigned short* __restrict__ ob) {
  const int n = blockIdx.x;
  const int t = threadIdx.x;
  const int c0 = t * 4;
  const int h = c0 >> 6;
  __shared__ float aS[64 * 256];
#pragma unroll 4
  for (int i = 0; i < 32; ++i) {
    const int f4 = i * 128 + t;
    const int bh = f4 >> 6;
    const int m4 = (f4 & 63) * 4;
    const float4 a = *(const float4*)&attn[(size_t)(bh * SEQ + n) * SEQ + m4];
    *(float4*)&aS[bh * 256 + (m4 ^ ((bh & 7) * 4))] = a;
  }
  __syncthreads();
  float acc[8][4];
#pragma unroll
  for (int b = 0; b < 8; ++b)
#pragma unroll
    for (int j = 0; j < 4; ++j) acc[b][j] = 0.0f;
  const int* idxr = idxm + n * SEQ;
  for (int mq = 0; mq < 64; ++mq) {
    const int4 rows = *(const int4*)&idxr[mq * 4];
    const float4 u0 = *(const float4*)&up[(size_t)rows.x * DIMC + c0];
    const float4 u1 = *(const float4*)&up[(size_t)rows.y * DIMC + c0];
    const float4 u2 = *(const float4*)&up[(size_t)rows.z * DIMC + c0];
    const float4 u3 = *(const float4*)&up[(size_t)rows.w * DIMC + c0];
    const int pbase = (mq * 4) ^ (h * 4);
#pragma unroll
    for (int b = 0; b < 8; ++b) {
      const float4 a = *(const float4*)&aS[(b * 8 + h) * 256 + pbase];
      acc[b][0] += a.x * u0.x + a.y * u1.x + a.z * u2.x + a.w * u3.x;
      acc[b][1] += a.x * u0.y + a.y * u1.y + a.z * u2.y + a.w * u3.y;
      acc[b][2] += a.x * u0.z + a.y * u1.z + a.z * u2.z + a.w * u3.z;
      acc[b][3] += a.x * u0.w + a.y * u1.w + a.z * u2.w + a.w * u3.w;
    }
  }
#pragma unroll
  for (int b = 0; b < 8; ++b) {
    ushort4 w;
    w.x = f2bf(acc[b][0]); w.y = f2bf(acc[b][1]);
    w.z = f2bf(acc[b][2]); w.w = f2bf(acc[b][3]);
    *(ushort4*)&ob[(size_t)(b * SEQ + n) * DIMC + c0] = w;
  }
}

// ---------------- K5: attn @ V, o += (bf16 RMW, no atomics) ------------------
__global__ __launch_bounds__(256) void av_kernel(const float* __restrict__ qkv,
    const float* __restrict__ attn, unsigned short* __restrict__ ob) {
  const int bh = blockIdx.y;
  const int b = bh >> 3, h = bh & 7;
  const int n0 = blockIdx.x * 64;
  const int t = threadIdx.x;
  const int tx = t & 15;
  const int ty = t >> 4;
  __shared__ float aS[32][68];
  __shared__ float vS[32][68];
  float acc[4][4];
#pragma unroll
  for (int i = 0; i < 4; ++i)
#pragma unroll
    for (int j = 0; j < 4; ++j) acc[i][j] = 0.0f;

  const int a_nn = t >> 2;
  const int a_mq = (t & 3) * 8;
  const int v_d4 = (t & 15) * 4;
  const int v_mm = t >> 4;

  for (int mc = 0; mc < 8; ++mc) {
    const int m0 = mc * 32;
    __syncthreads();
    {
      const float4 a0 = *(const float4*)&attn[(size_t)(bh * SEQ + n0 + a_nn) * SEQ + m0 + a_mq];
      const float4 a1 = *(const float4*)&attn[(size_t)(bh * SEQ + n0 + a_nn) * SEQ + m0 + a_mq + 4];
      aS[a_mq + 0][a_nn] = a0.x;
      aS[a_mq + 1][a_nn] = a0.y;
      aS[a_mq + 2][a_nn] = a0.z;
      aS[a_mq + 3][a_nn] = a0.w;
      aS[a_mq + 4][a_nn] = a1.x;
      aS[a_mq + 5][a_nn] = a1.y;
      aS[a_mq + 6][a_nn] = a1.z;
      aS[a_mq + 7][a_nn] = a1.w;
      *(float4*)&vS[v_mm][v_d4] =
          *(const float4*)&qkv[(size_t)(b * SEQ + m0 + v_mm) * 1536 + 1024 + h * 64 + v_d4];
      *(float4*)&vS[v_mm + 16][v_d4] =
          *(const float4*)&qkv[(size_t)(b * SEQ + m0 + v_mm + 16) * 1536 + 1024 + h * 64 + v_d4];
    }
    __syncthreads();
#pragma unroll 8
    for (int m = 0; m < 32; ++m) {
      float a[4], v[4];
      *(float4*)&a[0] = *(const float4*)&aS[m][ty * 4];
      *(float4*)&v[0] = *(const float4*)&vS[m][tx * 4];
#pragma unroll
      for (int i = 0; i < 4; ++i)
#pragma unroll
        for (int j = 0; j < 4; ++j) acc[i][j] += a[i] * v[j];
    }
  }
#pragma unroll
  for (int i = 0; i < 4; ++i) {
    const int n = n0 + ty * 4 + i;
    const size_t base = (size_t)(b * SEQ + n) * DIMC + h * 64 + tx * 4;
    ushort4 ov = *(ushort4*)&ob[base];
    ov.x = f2bf(bf2f(ov.x) + acc[i][0]);
    ov.y = f2bf(bf2f(ov.y) + acc[i][1]);
    ov.z = f2bf(bf2f(ov.z) + acc[i][2]);
    ov.w = f2bf(bf2f(ov.w) + acc[i][3]);
    *(ushort4*)&ob[base] = ov;
  }
}

extern "C" void kernel_launch(void* const* d_in, const int* in_sizes, int n_in,
                              void* d_out, int out_size, void* d_ws,
                              size_t ws_size, hipStream_t stream) {
  const float* x = (const float*)d_in[0];
  const float* ln_g = (const float*)d_in[1];
  const float* ln_b = (const float*)d_in[2];
  const float* w_qkv = (const float*)d_in[3];
  const float* up = (const float*)d_in[4];
  const float* w_out = (const float*)d_in[5];
  const float* b_out = (const float*)d_in[6];
  const int* idxm = (const int*)d_in[7];
  float* out = (float*)d_out;

  float* ws = (float*)d_ws;
  float* qkv = ws;                                   // 3,145,728 f
  float* attn = ws + 3145728;                        // 4,194,304 f
  unsigned short* xnb = (unsigned short*)(ws + 7340032);  // 1,048,576 bf16
  unsigned short* ob  = (unsigned short*)(ws + 7864320);  // 1,048,576 bf16
  unsigned short* wqt = (unsigned short*)(ws + 8388608);  //   786,432 bf16
  unsigned short* wot = (unsigned short*)(ws + 8781824);  //   262,144 bf16
  if (ws_size < (size_t)8912896 * sizeof(float)) return;

  tcast_kernel<<<dim3(24, 8), 256, 0, stream>>>(w_qkv, wqt, 512, 1536);
  tcast_kernel<<<dim3(8, 8), 256, 0, stream>>>(w_out, wot, 512, 512);
  ln_kernel<<<2048, 256, 0, stream>>>(x, ln_g, ln_b, xnb);
  mfma_gemm_bt<128, 128, false>
      <<<dim3(16, 12), 256, 0, stream>>>(xnb, wqt, nullptr, qkv, 2048, 512, 1536);
  qk_softmax_kernel<<<dim3(8, 64), 256, 0, stream>>>(qkv, attn);
  rpos_kernel<<<256, 128, 0, stream>>>(attn, up, idxm, ob);
  av_kernel<<<dim3(4, 64), 256, 0, stream>>>(qkv, attn, ob);
  mfma_gemm_bt<64, 64, true>
      <<<dim3(32, 8), 256, 0, stream>>>(ob, wot, b_out, out, 2048, 512, 512);
}

// Round 4
// 160.848 us; speedup vs baseline: 3.6674x; 1.1378x over previous
//
#include <hip/hip_runtime.h>
#include <math.h>

#define NB 8
#define SEQ 256
#define DIMC 512
#define NHEAD 8
#define DHEAD 64
#define SCALEF 0.125f

typedef __attribute__((ext_vector_type(8))) short s16x8;
typedef __attribute__((ext_vector_type(4))) float f32x4;

static __device__ __forceinline__ unsigned short f2bf(float f) {
  union { float f; unsigned u; } c; c.f = f;
  unsigned r = c.u + 0x7FFF + ((c.u >> 16) & 1);  // RNE
  return (unsigned short)(r >> 16);
}
static __device__ __forceinline__ float bf2f(unsigned short u) {
  union { unsigned u; float f; } c; c.u = ((unsigned)u) << 16;
  return c.f;
}

// ---------------- K0: transpose + cast fp32 W(KxN) -> bf16 WT(NxK) -----------
__global__ __launch_bounds__(256) void tcast_kernel(const float* __restrict__ W,
    unsigned short* __restrict__ WT, int K, int N) {
  const int n0 = blockIdx.x * 64, k0 = blockIdx.y * 64;
  __shared__ float tile[64][65];
  const int t = threadIdx.x;
#pragma unroll
  for (int i = 0; i < 16; ++i) {
    const int idx = i * 256 + t;
    const int kl = idx >> 6, nl = idx & 63;
    tile[kl][nl] = W[(size_t)(k0 + kl) * N + n0 + nl];
  }
  __syncthreads();
#pragma unroll
  for (int i = 0; i < 16; ++i) {
    const int idx = i * 256 + t;
    const int nl = idx >> 6, kl = idx & 63;
    WT[(size_t)(n0 + nl) * K + k0 + kl] = f2bf(tile[kl][nl]);
  }
}

// ---------------- K1: LayerNorm -> bf16 xn, 2048 blocks x 256 ----------------
__global__ __launch_bounds__(256) void ln_kernel(const float* __restrict__ x,
    const float* __restrict__ g, const float* __restrict__ bta,
    unsigned short* __restrict__ xnb) {
  const int row = blockIdx.x;
  const int t = threadIdx.x;
  const float2 v = ((const float2*)(x + (size_t)row * DIMC))[t];
  float s = v.x + v.y;
  float q = v.x * v.x + v.y * v.y;
#pragma unroll
  for (int off = 32; off > 0; off >>= 1) {
    s += __shfl_down(s, off);
    q += __shfl_down(q, off);
  }
  __shared__ float sh_s[4], sh_q[4];
  const int wave = t >> 6, lane = t & 63;
  if (lane == 0) { sh_s[wave] = s; sh_q[wave] = q; }
  __syncthreads();
  const float fs = sh_s[0] + sh_s[1] + sh_s[2] + sh_s[3];
  const float fq = sh_q[0] + sh_q[1] + sh_q[2] + sh_q[3];
  const float mean = fs * (1.0f / DIMC);
  const float inv = rsqrtf(fq * (1.0f / DIMC) - mean * mean + 1e-5f);
  const float2 gv = ((const float2*)g)[t];
  const float2 bv = ((const float2*)bta)[t];
  ushort2 o;
  o.x = f2bf((v.x - mean) * inv * gv.x + bv.x);
  o.y = f2bf((v.y - mean) * inv * gv.y + bv.y);
  ((ushort2*)(xnb + (size_t)row * DIMC))[t] = o;
}

// ---------------- bf16 MFMA GEMM: C(MxN) = A(MxK) @ BT(NxK)^T (+bias) --------
template <int BM, int BN, bool BIAS>
__global__ __launch_bounds__(256) void mfma_gemm_bt(
    const unsigned short* __restrict__ A, const unsigned short* __restrict__ BT,
    const float* __restrict__ bias, float* __restrict__ C,
    int M, int K, int N) {
  constexpr int TR = BM / 32;
  constexpr int TC = BN / 32;
  __shared__ unsigned short As[BM * 32];
  __shared__ unsigned short Bs[BN * 32];
  const int t = threadIdx.x;
  const int wave = t >> 6, lane = t & 63;
  const int wr = wave >> 1, wc = wave & 1;
  const int bm = blockIdx.x * BM, bn = blockIdx.y * BN;

  f32x4 acc[TR][TC] = {};

  const int fr = lane & 15, q = lane >> 4;
  const int kBlocks = K >> 5;
  for (int kb = 0; kb < kBlocks; ++kb) {
    const int k0 = kb << 5;
    __syncthreads();
#pragma unroll
    for (int c = 0; c < BM * 4 / 256; ++c) {
      const int chunk = c * 256 + t;
      const int row = chunk >> 2, j = chunk & 3;
      const s16x8 v = *(const s16x8*)(A + (size_t)(bm + row) * K + k0 + j * 8);
      *(s16x8*)(As + row * 32 + j * 8) = v;
    }
#pragma unroll
    for (int c = 0; c < BN * 4 / 256; ++c) {
      const int chunk = c * 256 + t;
      const int row = chunk >> 2, j = chunk & 3;
      const s16x8 v = *(const s16x8*)(BT + (size_t)(bn + row) * K + k0 + j * 8);
      *(s16x8*)(Bs + row * 32 + j * 8) = v;
    }
    __syncthreads();
    s16x8 af[TR], bfr[TC];
#pragma unroll
    for (int i = 0; i < TR; ++i) {
      const int row = wr * (BM / 2) + i * 16 + fr;
      af[i] = *(const s16x8*)(As + row * 32 + q * 8);
    }
#pragma unroll
    for (int j = 0; j < TC; ++j) {
      const int row = wc * (BN / 2) + j * 16 + fr;
      bfr[j] = *(const s16x8*)(Bs + row * 32 + q * 8);
    }
#pragma unroll
    for (int i = 0; i < TR; ++i)
#pragma unroll
      for (int j = 0; j < TC; ++j)
        acc[i][j] = __builtin_amdgcn_mfma_f32_16x16x32_bf16(af[i], bfr[j],
                                                            acc[i][j], 0, 0, 0);
  }
#pragma unroll
  for (int i = 0; i < TR; ++i) {
#pragma unroll
    for (int j = 0; j < TC; ++j) {
      const int col = bn + wc * (BN / 2) + j * 16 + fr;
      const float bv = BIAS ? bias[col] : 0.0f;
#pragma unroll
      for (int r = 0; r < 4; ++r) {
        const int row = bm + wr * (BM / 2) + i * 16 + q * 4 + r;
        C[(size_t)row * N + col] = acc[i][j][r] + bv;
      }
    }
  }
}

// ---------------- K3: QK^T * scale + softmax -> attn (fp32) ------------------
__global__ __launch_bounds__(256) void qk_softmax_kernel(
    const float* __restrict__ qkv, float* __restrict__ attn) {
  const int bh = blockIdx.y;
  const int b = bh >> 3, h = bh & 7;
  const int n0 = blockIdx.x * 32;
  const int t = threadIdx.x;
  const int tx = t & 15;
  const int ty = t >> 4;
  __shared__ float qS[64][34];
  __shared__ float kS[64][132];
  {
    const int d = t & 63, w = t >> 6;
    for (int nn = w; nn < 32; nn += 4)
      qS[d][nn] = qkv[(size_t)(b * SEQ + n0 + nn) * 1536 + h * 64 + d];
  }
  float acc[2][16];
#pragma unroll
  for (int i = 0; i < 2; ++i)
#pragma unroll
    for (int j = 0; j < 16; ++j) acc[i][j] = 0.0f;

  for (int mc = 0; mc < 2; ++mc) {
    __syncthreads();
    {
      const int d = t & 63, w = t >> 6;
      for (int mm = w; mm < 128; mm += 4)
        kS[d][mm] = qkv[(size_t)(b * SEQ + mc * 128 + mm) * 1536 + 512 + h * 64 + d];
    }
    __syncthreads();
#pragma unroll 8
    for (int d = 0; d < 64; ++d) {
      const float2 q2 = *(const float2*)&qS[d][ty * 2];
      const float4 k0 = *(const float4*)&kS[d][tx * 8];
      const float4 k1 = *(const float4*)&kS[d][tx * 8 + 4];
      const int c = mc * 8;
      acc[0][c + 0] += q2.x * k0.x; acc[0][c + 1] += q2.x * k0.y;
      acc[0][c + 2] += q2.x * k0.z; acc[0][c + 3] += q2.x * k0.w;
      acc[0][c + 4] += q2.x * k1.x; acc[0][c + 5] += q2.x * k1.y;
      acc[0][c + 6] += q2.x * k1.z; acc[0][c + 7] += q2.x * k1.w;
      acc[1][c + 0] += q2.y * k0.x; acc[1][c + 1] += q2.y * k0.y;
      acc[1][c + 2] += q2.y * k0.z; acc[1][c + 3] += q2.y * k0.w;
      acc[1][c + 4] += q2.y * k1.x; acc[1][c + 5] += q2.y * k1.y;
      acc[1][c + 6] += q2.y * k1.z; acc[1][c + 7] += q2.y * k1.w;
    }
  }
#pragma unroll
  for (int i = 0; i < 2; ++i) {
    const int n = n0 + ty * 2 + i;
    float mx = -1e30f;
#pragma unroll
    for (int j = 0; j < 16; ++j) {
      acc[i][j] *= SCALEF;
      mx = fmaxf(mx, acc[i][j]);
    }
#pragma unroll
    for (int off = 1; off < 16; off <<= 1) mx = fmaxf(mx, __shfl_xor(mx, off));
    float sum = 0.0f;
#pragma unroll
    for (int j = 0; j < 16; ++j) {
      acc[i][j] = __expf(acc[i][j] - mx);
      sum += acc[i][j];
    }
#pragma unroll
    for (int off = 1; off < 16; off <<= 1) sum += __shfl_xor(sum, off);
    const float inv = 1.0f / sum;
    const size_t abase = (size_t)(bh * SEQ + n) * SEQ;
    float4 w;
    w.x = acc[i][0] * inv; w.y = acc[i][1] * inv; w.z = acc[i][2] * inv; w.w = acc[i][3] * inv;
    *(float4*)&attn[abase + tx * 8] = w;
    w.x = acc[i][4] * inv; w.y = acc[i][5] * inv; w.z = acc[i][6] * inv; w.w = acc[i][7] * inv;
    *(float4*)&attn[abase + tx * 8 + 4] = w;
    w.x = acc[i][8] * inv; w.y = acc[i][9] * inv; w.z = acc[i][10] * inv; w.w = acc[i][11] * inv;
    *(float4*)&attn[abase + 128 + tx * 8] = w;
    w.x = acc[i][12] * inv; w.y = acc[i][13] * inv; w.z = acc[i][14] * inv; w.w = acc[i][15] * inv;
    *(float4*)&attn[abase + 128 + tx * 8 + 4] = w;
  }
}

// ---------------- K4: relative-position term -> o (bf16, init) ---------------
// Wave-per-(n,h): grid 512 x 256 threads (4 waves). Wave stages its attn slice
// [8b][256m] into a skewed LDS region; up-row index computed arithmetically
// (matches _index_map); m split 4-way over lane groups, shfl-reduced.
#define RSTRIDE 280  // 256 + up-to-24 skew headroom
__global__ __launch_bounds__(256) void rpos_kernel(const float* __restrict__ attn,
    const float* __restrict__ up, const int* __restrict__ idxm,
    unsigned short* __restrict__ ob) {
  __shared__ float aS[4][8 * RSTRIDE];  // 35,840 B
  const int t = threadIdx.x;
  const int wave = t >> 6, lane = t & 63;
  const int g = lane >> 4, dg = lane & 15;  // m-group, d-quad
  const int pair = blockIdx.x * 4 + wave;
  const int n = pair >> 3, h = pair & 7;
  float* aW = aS[wave];

  // stage attn[b, h, n, :] for b=0..7 (each b: 64 lanes x float4 = 1KB dense)
  const int m4 = lane * 4;
  const int sm4 = m4 + ((m4 >> 6) << 3);  // skew: +8 floats per 64-m block
#pragma unroll
  for (int b = 0; b < 8; ++b) {
    const float4 v = *(const float4*)&attn[(size_t)((b * 8 + h) * SEQ + n) * SEQ + m4];
    *(float4*)&aW[b * RSTRIDE + sm4] = v;
  }
  __syncthreads();

  const int xn = n >> 4, yn = n & 15;
  float acc[8][4];
#pragma unroll
  for (int b = 0; b < 8; ++b)
#pragma unroll
    for (int j = 0; j < 4; ++j) acc[b][j] = 0.0f;

  const int mbase = g * 64;
  const int sbase = g * 72;  // skewed base = g*64 + g*8
#pragma unroll 4
  for (int mm = 0; mm < 64; ++mm) {
    const int m = mbase + mm;
    const int xm = m >> 4, ym = m & 15;
    const int row = (xn - xm + 15) * 31 + (yn - ym + 15);
    const float4 u = *(const float4*)&up[(size_t)row * DIMC + h * 64 + dg * 4];
    float ab[8];
#pragma unroll
    for (int b = 0; b < 8; ++b) ab[b] = aW[b * RSTRIDE + sbase + mm];
#pragma unroll
    for (int b = 0; b < 8; ++b) {
      acc[b][0] += ab[b] * u.x;
      acc[b][1] += ab[b] * u.y;
      acc[b][2] += ab[b] * u.z;
      acc[b][3] += ab[b] * u.w;
    }
  }
  // cross-group reduce (groups differ in lane bits 4-5)
#pragma unroll
  for (int b = 0; b < 8; ++b)
#pragma unroll
    for (int j = 0; j < 4; ++j) {
      float v = acc[b][j];
      v += __shfl_xor(v, 16);
      v += __shfl_xor(v, 32);
      acc[b][j] = v;
    }
  // group g writes b = 2g, 2g+1
#pragma unroll
  for (int k = 0; k < 2; ++k) {
    const int b = g * 2 + k;
    ushort4 w;
    w.x = f2bf(acc[b][0]); w.y = f2bf(acc[b][1]);
    w.z = f2bf(acc[b][2]); w.w = f2bf(acc[b][3]);
    *(ushort4*)&ob[(size_t)(b * SEQ + n) * DIMC + h * 64 + dg * 4] = w;
  }
}

// ---------------- K5: attn @ V, o += (bf16 RMW, no atomics) ------------------
__global__ __launch_bounds__(256) void av_kernel(const float* __restrict__ qkv,
    const float* __restrict__ attn, unsigned short* __restrict__ ob) {
  const int bh = blockIdx.y;
  const int b = bh >> 3, h = bh & 7;
  const int n0 = blockIdx.x * 64;
  const int t = threadIdx.x;
  const int tx = t & 15;
  const int ty = t >> 4;
  __shared__ float aS[32][68];
  __shared__ float vS[32][68];
  float acc[4][4];
#pragma unroll
  for (int i = 0; i < 4; ++i)
#pragma unroll
    for (int j = 0; j < 4; ++j) acc[i][j] = 0.0f;

  const int a_nn = t >> 2;
  const int a_mq = (t & 3) * 8;
  const int v_d4 = (t & 15) * 4;
  const int v_mm = t >> 4;

  for (int mc = 0; mc < 8; ++mc) {
    const int m0 = mc * 32;
    __syncthreads();
    {
      const float4 a0 = *(const float4*)&attn[(size_t)(bh * SEQ + n0 + a_nn) * SEQ + m0 + a_mq];
      const float4 a1 = *(const float4*)&attn[(size_t)(bh * SEQ + n0 + a_nn) * SEQ + m0 + a_mq + 4];
      aS[a_mq + 0][a_nn] = a0.x;
      aS[a_mq + 1][a_nn] = a0.y;
      aS[a_mq + 2][a_nn] = a0.z;
      aS[a_mq + 3][a_nn] = a0.w;
      aS[a_mq + 4][a_nn] = a1.x;
      aS[a_mq + 5][a_nn] = a1.y;
      aS[a_mq + 6][a_nn] = a1.z;
      aS[a_mq + 7][a_nn] = a1.w;
      *(float4*)&vS[v_mm][v_d4] =
          *(const float4*)&qkv[(size_t)(b * SEQ + m0 + v_mm) * 1536 + 1024 + h * 64 + v_d4];
      *(float4*)&vS[v_mm + 16][v_d4] =
          *(const float4*)&qkv[(size_t)(b * SEQ + m0 + v_mm + 16) * 1536 + 1024 + h * 64 + v_d4];
    }
    __syncthreads();
#pragma unroll 8
    for (int m = 0; m < 32; ++m) {
      float a[4], v[4];
      *(float4*)&a[0] = *(const float4*)&aS[m][ty * 4];
      *(float4*)&v[0] = *(const float4*)&vS[m][tx * 4];
#pragma unroll
      for (int i = 0; i < 4; ++i)
#pragma unroll
        for (int j = 0; j < 4; ++j) acc[i][j] += a[i] * v[j];
    }
  }
#pragma unroll
  for (int i = 0; i < 4; ++i) {
    const int n = n0 + ty * 4 + i;
    const size_t base = (size_t)(b * SEQ + n) * DIMC + h * 64 + tx * 4;
    ushort4 ov = *(ushort4*)&ob[base];
    ov.x = f2bf(bf2f(ov.x) + acc[i][0]);
    ov.y = f2bf(bf2f(ov.y) + acc[i][1]);
    ov.z = f2bf(bf2f(ov.z) + acc[i][2]);
    ov.w = f2bf(bf2f(ov.w) + acc[i][3]);
    *(ushort4*)&ob[base] = ov;
  }
}

extern "C" void kernel_launch(void* const* d_in, const int* in_sizes, int n_in,
                              void* d_out, int out_size, void* d_ws,
                              size_t ws_size, hipStream_t stream) {
  const float* x = (const float*)d_in[0];
  const float* ln_g = (const float*)d_in[1];
  const float* ln_b = (const float*)d_in[2];
  const float* w_qkv = (const float*)d_in[3];
  const float* up = (const float*)d_in[4];
  const float* w_out = (const float*)d_in[5];
  const float* b_out = (const float*)d_in[6];
  const int* idxm = (const int*)d_in[7];
  float* out = (float*)d_out;

  float* ws = (float*)d_ws;
  float* qkv = ws;                                   // 3,145,728 f
  float* attn = ws + 3145728;                        // 4,194,304 f
  unsigned short* xnb = (unsigned short*)(ws + 7340032);  // 1,048,576 bf16
  unsigned short* ob  = (unsigned short*)(ws + 7864320);  // 1,048,576 bf16
  unsigned short* wqt = (unsigned short*)(ws + 8388608);  //   786,432 bf16
  unsigned short* wot = (unsigned short*)(ws + 8781824);  //   262,144 bf16
  if (ws_size < (size_t)8912896 * sizeof(float)) return;

  tcast_kernel<<<dim3(24, 8), 256, 0, stream>>>(w_qkv, wqt, 512, 1536);
  tcast_kernel<<<dim3(8, 8), 256, 0, stream>>>(w_out, wot, 512, 512);
  ln_kernel<<<2048, 256, 0, stream>>>(x, ln_g, ln_b, xnb);
  mfma_gemm_bt<128, 128, false>
      <<<dim3(16, 12), 256, 0, stream>>>(xnb, wqt, nullptr, qkv, 2048, 512, 1536);
  qk_softmax_kernel<<<dim3(8, 64), 256, 0, stream>>>(qkv, attn);
  rpos_kernel<<<512, 256, 0, stream>>>(attn, up, idxm, ob);
  av_kernel<<<dim3(4, 64), 256, 0, stream>>>(qkv, attn, ob);
  mfma_gemm_bt<64, 64, true>
      <<<dim3(32, 8), 256, 0, stream>>>(ob, wot, b_out, out, 2048, 512, 512);
}

// Round 5
// 127.932 us; speedup vs baseline: 4.6110x; 1.2573x over previous
//
#include <hip/hip_runtime.h>
#include <math.h>

#define NB 8
#define SEQ 256
#define DIMC 512
#define NHEAD 8
#define DHEAD 64
#define SCALEF 0.125f

typedef __attribute__((ext_vector_type(8))) short s16x8;
typedef __attribute__((ext_vector_type(4))) float f32x4;

static __device__ __forceinline__ unsigned short f2bf(float f) {
  union { float f; unsigned u; } c; c.f = f;
  unsigned r = c.u + 0x7FFF + ((c.u >> 16) & 1);  // RNE
  return (unsigned short)(r >> 16);
}
static __device__ __forceinline__ float bf2f(unsigned short u) {
  union { unsigned u; float f; } c; c.u = ((unsigned)u) << 16;
  return c.f;
}

// ---------------- K0: transpose + cast fp32 W(KxN) -> bf16 WT(NxK) -----------
__global__ __launch_bounds__(256) void tcast_kernel(const float* __restrict__ W,
    unsigned short* __restrict__ WT, int K, int N) {
  const int n0 = blockIdx.x * 64, k0 = blockIdx.y * 64;
  __shared__ float tile[64][65];
  const int t = threadIdx.x;
#pragma unroll
  for (int i = 0; i < 16; ++i) {
    const int idx = i * 256 + t;
    const int kl = idx >> 6, nl = idx & 63;
    tile[kl][nl] = W[(size_t)(k0 + kl) * N + n0 + nl];
  }
  __syncthreads();
#pragma unroll
  for (int i = 0; i < 16; ++i) {
    const int idx = i * 256 + t;
    const int nl = idx >> 6, kl = idx & 63;
    WT[(size_t)(n0 + nl) * K + k0 + kl] = f2bf(tile[kl][nl]);
  }
}

// ---------------- K1: LayerNorm -> bf16 xn ----------------
__global__ __launch_bounds__(256) void ln_kernel(const float* __restrict__ x,
    const float* __restrict__ g, const float* __restrict__ bta,
    unsigned short* __restrict__ xnb) {
  const int row = blockIdx.x;
  const int t = threadIdx.x;
  const float2 v = ((const float2*)(x + (size_t)row * DIMC))[t];
  float s = v.x + v.y;
  float q = v.x * v.x + v.y * v.y;
#pragma unroll
  for (int off = 32; off > 0; off >>= 1) {
    s += __shfl_down(s, off);
    q += __shfl_down(q, off);
  }
  __shared__ float sh_s[4], sh_q[4];
  const int wave = t >> 6, lane = t & 63;
  if (lane == 0) { sh_s[wave] = s; sh_q[wave] = q; }
  __syncthreads();
  const float fs = sh_s[0] + sh_s[1] + sh_s[2] + sh_s[3];
  const float fq = sh_q[0] + sh_q[1] + sh_q[2] + sh_q[3];
  const float mean = fs * (1.0f / DIMC);
  const float inv = rsqrtf(fq * (1.0f / DIMC) - mean * mean + 1e-5f);
  const float2 gv = ((const float2*)g)[t];
  const float2 bv = ((const float2*)bta)[t];
  ushort2 o;
  o.x = f2bf((v.x - mean) * inv * gv.x + bv.x);
  o.y = f2bf((v.y - mean) * inv * gv.y + bv.y);
  ((ushort2*)(xnb + (size_t)row * DIMC))[t] = o;
}

// ---------------- bf16 MFMA GEMM: C = A(MxK) @ BT(NxK)^T (+bias) -------------
template <int BM, int BN, bool BIAS, bool OUTBF>
__global__ __launch_bounds__(256) void mfma_gemm_bt(
    const unsigned short* __restrict__ A, const unsigned short* __restrict__ BT,
    const float* __restrict__ bias, void* __restrict__ Cv,
    int M, int K, int N) {
  constexpr int TR = BM / 32;
  constexpr int TC = BN / 32;
  __shared__ unsigned short As[BM * 32];
  __shared__ unsigned short Bs[BN * 32];
  const int t = threadIdx.x;
  const int wave = t >> 6, lane = t & 63;
  const int wr = wave >> 1, wc = wave & 1;
  const int bm = blockIdx.x * BM, bn = blockIdx.y * BN;

  f32x4 acc[TR][TC] = {};

  const int fr = lane & 15, q = lane >> 4;
  const int kBlocks = K >> 5;
  for (int kb = 0; kb < kBlocks; ++kb) {
    const int k0 = kb << 5;
    __syncthreads();
#pragma unroll
    for (int c = 0; c < BM * 4 / 256; ++c) {
      const int chunk = c * 256 + t;
      const int row = chunk >> 2, j = chunk & 3;
      const s16x8 v = *(const s16x8*)(A + (size_t)(bm + row) * K + k0 + j * 8);
      *(s16x8*)(As + row * 32 + j * 8) = v;
    }
#pragma unroll
    for (int c = 0; c < BN * 4 / 256; ++c) {
      const int chunk = c * 256 + t;
      const int row = chunk >> 2, j = chunk & 3;
      const s16x8 v = *(const s16x8*)(BT + (size_t)(bn + row) * K + k0 + j * 8);
      *(s16x8*)(Bs + row * 32 + j * 8) = v;
    }
    __syncthreads();
    s16x8 af[TR], bfr[TC];
#pragma unroll
    for (int i = 0; i < TR; ++i) {
      const int row = wr * (BM / 2) + i * 16 + fr;
      af[i] = *(const s16x8*)(As + row * 32 + q * 8);
    }
#pragma unroll
    for (int j = 0; j < TC; ++j) {
      const int row = wc * (BN / 2) + j * 16 + fr;
      bfr[j] = *(const s16x8*)(Bs + row * 32 + q * 8);
    }
#pragma unroll
    for (int i = 0; i < TR; ++i)
#pragma unroll
      for (int j = 0; j < TC; ++j)
        acc[i][j] = __builtin_amdgcn_mfma_f32_16x16x32_bf16(af[i], bfr[j],
                                                            acc[i][j], 0, 0, 0);
  }
#pragma unroll
  for (int i = 0; i < TR; ++i) {
#pragma unroll
    for (int j = 0; j < TC; ++j) {
      const int col = bn + wc * (BN / 2) + j * 16 + fr;
      const float bv = BIAS ? bias[col] : 0.0f;
#pragma unroll
      for (int r = 0; r < 4; ++r) {
        const int row = bm + wr * (BM / 2) + i * 16 + q * 4 + r;
        if constexpr (OUTBF) {
          ((unsigned short*)Cv)[(size_t)row * N + col] = f2bf(acc[i][j][r] + bv);
        } else {
          ((float*)Cv)[(size_t)row * N + col] = acc[i][j][r] + bv;
        }
      }
    }
  }
}

// ---------------- K3: fused QK^T -> softmax -> AV (MFMA), per (b,h,ntile) ----
// grid (4 ntiles, 64 bh) x 256 thr. Writes attn (bf16) and o_av (bf16).
#define PSTR 264   // P/vT LDS stride in bf16 (528 B: fr*4-bank pattern, 2-way free)
#define KSTR 72    // K LDS stride in bf16 (144 B)
__global__ __launch_bounds__(256) void fused_attn_kernel(
    const unsigned short* __restrict__ qkvb, unsigned short* __restrict__ attnb,
    unsigned short* __restrict__ oav) {
  __shared__ unsigned short kv_lds[256 * KSTR];  // K stage, then reused for V^T
  __shared__ unsigned short p_lds[64 * PSTR];
  const int bh = blockIdx.y, b = bh >> 3, h = bh & 7;
  const int n0 = blockIdx.x * 64;
  const int t = threadIdx.x, wave = t >> 6, lane = t & 63;
  const int fr = lane & 15, q4 = lane >> 4;

  // stage K[m][d] (head h) into kv_lds
  {
    const int dc = (t & 7) * 8;
#pragma unroll
    for (int p = 0; p < 8; ++p) {
      const int m = p * 32 + (t >> 3);
      const s16x8 v =
          *(const s16x8*)(qkvb + (size_t)(b * SEQ + m) * 1536 + 512 + h * 64 + dc);
      *(s16x8*)(kv_lds + m * KSTR + dc) = v;
    }
  }
  // q A-frags straight from global (16 lanes scattered, only 2 loads)
  s16x8 qf[2];
  {
    const size_t qrow = (size_t)(b * SEQ + n0 + wave * 16 + fr) * 1536 + h * 64;
#pragma unroll
    for (int ks = 0; ks < 2; ++ks)
      qf[ks] = *(const s16x8*)(qkvb + qrow + ks * 32 + q4 * 8);
  }
  __syncthreads();

  // S = q . k^T  (C-layout: col m = fr, row n = q4*4+r)
  f32x4 s[16];
#pragma unroll
  for (int mt = 0; mt < 16; ++mt) s[mt] = (f32x4){0.f, 0.f, 0.f, 0.f};
#pragma unroll
  for (int ks = 0; ks < 2; ++ks)
#pragma unroll
    for (int mt = 0; mt < 16; ++mt) {
      const s16x8 kf =
          *(const s16x8*)(kv_lds + (mt * 16 + fr) * KSTR + ks * 32 + q4 * 8);
      s[mt] = __builtin_amdgcn_mfma_f32_16x16x32_bf16(qf[ks], kf, s[mt], 0, 0, 0);
    }

  // softmax: per lane 4 rows x 16 m-cols; reduce across fr lanes (xor 1,2,4,8)
  float mx[4] = {-1e30f, -1e30f, -1e30f, -1e30f};
#pragma unroll
  for (int mt = 0; mt < 16; ++mt)
#pragma unroll
    for (int r = 0; r < 4; ++r) {
      s[mt][r] *= SCALEF;
      mx[r] = fmaxf(mx[r], s[mt][r]);
    }
#pragma unroll
  for (int r = 0; r < 4; ++r) {
    mx[r] = fmaxf(mx[r], __shfl_xor(mx[r], 1));
    mx[r] = fmaxf(mx[r], __shfl_xor(mx[r], 2));
    mx[r] = fmaxf(mx[r], __shfl_xor(mx[r], 4));
    mx[r] = fmaxf(mx[r], __shfl_xor(mx[r], 8));
  }
  float sum[4] = {0.f, 0.f, 0.f, 0.f};
#pragma unroll
  for (int mt = 0; mt < 16; ++mt)
#pragma unroll
    for (int r = 0; r < 4; ++r) {
      s[mt][r] = __expf(s[mt][r] - mx[r]);
      sum[r] += s[mt][r];
    }
#pragma unroll
  for (int r = 0; r < 4; ++r) {
    sum[r] += __shfl_xor(sum[r], 1);
    sum[r] += __shfl_xor(sum[r], 2);
    sum[r] += __shfl_xor(sum[r], 4);
    sum[r] += __shfl_xor(sum[r], 8);
  }
  const float inv0 = 1.0f / sum[0], inv1 = 1.0f / sum[1];
  const float inv2 = 1.0f / sum[2], inv3 = 1.0f / sum[3];
  const float invs[4] = {inv0, inv1, inv2, inv3};

  __syncthreads();  // all waves done reading kv_lds (K) before V^T overwrite

  // write P -> p_lds (bf16, [n][m]) and stage V^T into kv_lds ([d][m], PSTR)
  {
    const int nb = wave * 16 + q4 * 4;
#pragma unroll
    for (int mt = 0; mt < 16; ++mt)
#pragma unroll
      for (int r = 0; r < 4; ++r)
        p_lds[(nb + r) * PSTR + mt * 16 + fr] = f2bf(s[mt][r] * invs[r]);
  }
  {
    const int dc = (t & 7) * 8;
#pragma unroll
    for (int p = 0; p < 8; ++p) {
      const int m = p * 32 + (t >> 3);
      const s16x8 v =
          *(const s16x8*)(qkvb + (size_t)(b * SEQ + m) * 1536 + 1024 + h * 64 + dc);
#pragma unroll
      for (int j = 0; j < 8; ++j) kv_lds[(dc + j) * PSTR + m] = v[j];
    }
  }
  __syncthreads();

  // copy P -> global attn (bf16) for the rpos kernel
#pragma unroll
  for (int p = 0; p < 8; ++p) {
    const int idx = p * 256 + t;
    const int row = idx >> 5, mc = (idx & 31) * 8;
    *(s16x8*)(attnb + (size_t)(bh * SEQ + n0 + row) * SEQ + mc) =
        *(const s16x8*)(p_lds + row * PSTR + mc);
  }

  // O = P . V  (A = P rows n, BT = V^T rows d)
  f32x4 o[4];
#pragma unroll
  for (int dt = 0; dt < 4; ++dt) o[dt] = (f32x4){0.f, 0.f, 0.f, 0.f};
#pragma unroll
  for (int ks = 0; ks < 8; ++ks) {
    const s16x8 pf =
        *(const s16x8*)(p_lds + (wave * 16 + fr) * PSTR + ks * 32 + q4 * 8);
#pragma unroll
    for (int dt = 0; dt < 4; ++dt) {
      const s16x8 vf =
          *(const s16x8*)(kv_lds + (dt * 16 + fr) * PSTR + ks * 32 + q4 * 8);
      o[dt] = __builtin_amdgcn_mfma_f32_16x16x32_bf16(pf, vf, o[dt], 0, 0, 0);
    }
  }
#pragma unroll
  for (int dt = 0; dt < 4; ++dt)
#pragma unroll
    for (int r = 0; r < 4; ++r) {
      const int n = n0 + wave * 16 + q4 * 4 + r;
      oav[(size_t)(b * SEQ + n) * DIMC + h * 64 + dt * 16 + fr] = f2bf(o[dt][r]);
    }
}

// ---------------- K4: rpos gather + o_av add -> ob (bf16) --------------------
// Wave-per-(n,h); attn is bf16 now. up-row index computed arithmetically.
#define RSTRIDE 280
__global__ __launch_bounds__(256) void rpos_kernel(
    const unsigned short* __restrict__ attnb, const float* __restrict__ up,
    unsigned short* __restrict__ ob) {
  __shared__ float aS[4][8 * RSTRIDE];
  const int t = threadIdx.x;
  const int wave = t >> 6, lane = t & 63;
  const int g = lane >> 4, dg = lane & 15;
  const int pair = blockIdx.x * 4 + wave;
  const int n = pair >> 3, h = pair & 7;
  float* aW = aS[wave];

  const int m4 = lane * 4;
  const int sm4 = m4 + ((m4 >> 6) << 3);
#pragma unroll
  for (int b = 0; b < 8; ++b) {
    const ushort4 v =
        *(const ushort4*)&attnb[(size_t)((b * 8 + h) * SEQ + n) * SEQ + m4];
    float4 f;
    f.x = bf2f(v.x); f.y = bf2f(v.y); f.z = bf2f(v.z); f.w = bf2f(v.w);
    *(float4*)&aW[b * RSTRIDE + sm4] = f;
  }
  __syncthreads();

  const int xn = n >> 4, yn = n & 15;
  float acc[8][4];
#pragma unroll
  for (int b = 0; b < 8; ++b)
#pragma unroll
    for (int j = 0; j < 4; ++j) acc[b][j] = 0.0f;

  const int mbase = g * 64;
  const int sbase = g * 72;
#pragma unroll 4
  for (int mm = 0; mm < 64; ++mm) {
    const int m = mbase + mm;
    const int xm = m >> 4, ym = m & 15;
    const int row = (xn - xm + 15) * 31 + (yn - ym + 15);
    const float4 u = *(const float4*)&up[(size_t)row * DIMC + h * 64 + dg * 4];
    float ab[8];
#pragma unroll
    for (int b = 0; b < 8; ++b) ab[b] = aW[b * RSTRIDE + sbase + mm];
#pragma unroll
    for (int b = 0; b < 8; ++b) {
      acc[b][0] += ab[b] * u.x;
      acc[b][1] += ab[b] * u.y;
      acc[b][2] += ab[b] * u.z;
      acc[b][3] += ab[b] * u.w;
    }
  }
#pragma unroll
  for (int b = 0; b < 8; ++b)
#pragma unroll
    for (int j = 0; j < 4; ++j) {
      float v = acc[b][j];
      v += __shfl_xor(v, 16);
      v += __shfl_xor(v, 32);
      acc[b][j] = v;
    }
#pragma unroll
  for (int k = 0; k < 2; ++k) {
    const int b = g * 2 + k;
    const size_t base = (size_t)(b * SEQ + n) * DIMC + h * 64 + dg * 4;
    ushort4 pv = *(ushort4*)&ob[base];
    ushort4 w;
    w.x = f2bf(bf2f(pv.x) + acc[b][0]);
    w.y = f2bf(bf2f(pv.y) + acc[b][1]);
    w.z = f2bf(bf2f(pv.z) + acc[b][2]);
    w.w = f2bf(bf2f(pv.w) + acc[b][3]);
    *(ushort4*)&ob[base] = w;
  }
}

extern "C" void kernel_launch(void* const* d_in, const int* in_sizes, int n_in,
                              void* d_out, int out_size, void* d_ws,
                              size_t ws_size, hipStream_t stream) {
  const float* x = (const float*)d_in[0];
  const float* ln_g = (const float*)d_in[1];
  const float* ln_b = (const float*)d_in[2];
  const float* w_qkv = (const float*)d_in[3];
  const float* up = (const float*)d_in[4];
  const float* w_out = (const float*)d_in[5];
  const float* b_out = (const float*)d_in[6];
  float* out = (float*)d_out;

  unsigned short* u = (unsigned short*)d_ws;
  unsigned short* qkvb = u;                 // 3,145,728
  unsigned short* attnb = u + 3145728;      // 4,194,304
  unsigned short* xnb = u + 7340032;        // 1,048,576
  unsigned short* ob = u + 8388608;         // 1,048,576  (o_av then final o)
  unsigned short* wqt = u + 9437184;        //   786,432
  unsigned short* wot = u + 10223616;       //   262,144
  if (ws_size < (size_t)10485760 * sizeof(unsigned short)) return;  // ~21 MB

  tcast_kernel<<<dim3(24, 8), 256, 0, stream>>>(w_qkv, wqt, 512, 1536);
  tcast_kernel<<<dim3(8, 8), 256, 0, stream>>>(w_out, wot, 512, 512);
  ln_kernel<<<2048, 256, 0, stream>>>(x, ln_g, ln_b, xnb);
  mfma_gemm_bt<128, 128, false, true>
      <<<dim3(16, 12), 256, 0, stream>>>(xnb, wqt, nullptr, qkvb, 2048, 512, 1536);
  fused_attn_kernel<<<dim3(4, 64), 256, 0, stream>>>(qkvb, attnb, ob);
  rpos_kernel<<<512, 256, 0, stream>>>(attnb, up, ob);
  mfma_gemm_bt<64, 64, true, false>
      <<<dim3(32, 8), 256, 0, stream>>>(ob, wot, b_out, out, 2048, 512, 512);
}

// Round 6
// 123.202 us; speedup vs baseline: 4.7880x; 1.0384x over previous
//
#include <hip/hip_runtime.h>
#include <math.h>

#define NB 8
#define SEQ 256
#define DIMC 512
#define NHEAD 8
#define DHEAD 64
#define SCALEF 0.125f

typedef __attribute__((ext_vector_type(8))) short s16x8;
typedef __attribute__((ext_vector_type(4))) float f32x4;

typedef __attribute__((address_space(3))) unsigned int lds_u32_t;
typedef const __attribute__((address_space(1))) unsigned int g_u32_t;
static __device__ __forceinline__ void gl_lds16(const void* gsrc, void* ldst) {
  __builtin_amdgcn_global_load_lds((g_u32_t*)gsrc, (lds_u32_t*)ldst, 16, 0, 0);
}

static __device__ __forceinline__ unsigned short f2bf(float f) {
  union { float f; unsigned u; } c; c.f = f;
  unsigned r = c.u + 0x7FFF + ((c.u >> 16) & 1);  // RNE
  return (unsigned short)(r >> 16);
}
static __device__ __forceinline__ float bf2f(unsigned short u) {
  union { unsigned u; float f; } c; c.u = ((unsigned)u) << 16;
  return c.f;
}

// ---------------- K0: fused prep: tcast(w_qkv), tcast(w_out), up->bf16, LN ---
static __device__ void tcast_body(const float* __restrict__ W,
    unsigned short* __restrict__ WT, int K, int N, int n0, int k0, int t,
    float (*tile)[65]) {
#pragma unroll
  for (int i = 0; i < 16; ++i) {
    const int idx = i * 256 + t;
    const int kl = idx >> 6, nl = idx & 63;
    tile[kl][nl] = W[(size_t)(k0 + kl) * N + n0 + nl];
  }
  __syncthreads();
#pragma unroll
  for (int i = 0; i < 16; ++i) {
    const int idx = i * 256 + t;
    const int nl = idx >> 6, kl = idx & 63;
    WT[(size_t)(n0 + nl) * K + k0 + kl] = f2bf(tile[kl][nl]);
  }
}

__global__ __launch_bounds__(256) void prep_kernel(const float* __restrict__ x,
    const float* __restrict__ g, const float* __restrict__ bta,
    const float* __restrict__ w_qkv, const float* __restrict__ w_out,
    const float* __restrict__ up, unsigned short* __restrict__ xnb,
    unsigned short* __restrict__ wqt, unsigned short* __restrict__ wot,
    unsigned short* __restrict__ upb) {
  __shared__ float tile[64][65];
  __shared__ float sh_s[4], sh_q[4];
  const int t = threadIdx.x;
  const int bid = blockIdx.x;
  if (bid < 192) {                     // w_qkv: 24 n-tiles x 8 k-tiles
    tcast_body(w_qkv, wqt, 512, 1536, (bid % 24) * 64, (bid / 24) * 64, t, tile);
  } else if (bid < 256) {              // w_out: 8 x 8
    const int b2 = bid - 192;
    tcast_body(w_out, wot, 512, 512, (b2 % 8) * 64, (b2 / 8) * 64, t, tile);
  } else if (bid < 497) {              // up cast: 961*512 = 492,032 elems
    const int base = (bid - 256) * 2048 + t * 4;
#pragma unroll
    for (int it = 0; it < 2; ++it) {
      const int i = base + it * 1024;
      if (i < 492032) {
        const float4 v = *(const float4*)&up[i];
        ushort4 w;
        w.x = f2bf(v.x); w.y = f2bf(v.y); w.z = f2bf(v.z); w.w = f2bf(v.w);
        *(ushort4*)&upb[i] = w;
      }
    }
  } else {                             // LayerNorm rows 0..2047
    const int row = bid - 497;
    const float2 v = ((const float2*)(x + (size_t)row * DIMC))[t];
    float s = v.x + v.y;
    float q = v.x * v.x + v.y * v.y;
#pragma unroll
    for (int off = 32; off > 0; off >>= 1) {
      s += __shfl_down(s, off);
      q += __shfl_down(q, off);
    }
    const int wave = t >> 6, lane = t & 63;
    if (lane == 0) { sh_s[wave] = s; sh_q[wave] = q; }
    __syncthreads();
    const float fs = sh_s[0] + sh_s[1] + sh_s[2] + sh_s[3];
    const float fq = sh_q[0] + sh_q[1] + sh_q[2] + sh_q[3];
    const float mean = fs * (1.0f / DIMC);
    const float inv = rsqrtf(fq * (1.0f / DIMC) - mean * mean + 1e-5f);
    const float2 gv = ((const float2*)g)[t];
    const float2 bv = ((const float2*)bta)[t];
    ushort2 o;
    o.x = f2bf((v.x - mean) * inv * gv.x + bv.x);
    o.y = f2bf((v.y - mean) * inv * gv.y + bv.y);
    ((ushort2*)(xnb + (size_t)row * DIMC))[t] = o;
  }
}

// ---------------- bf16 MFMA GEMM: C = A(MxK) @ BT(NxK)^T (+bias) -------------
// global_load_lds(16B) staging with XOR chunk swizzle: phys chunk (row, jp)
// holds logical k-chunk jp ^ ((row>>1)&3)  -> frag ds_read_b128 is 2-way max.
template <int BM, int BN, bool BIAS, bool OUTBF>
__global__ __launch_bounds__(256) void mfma_gemm_bt(
    const unsigned short* __restrict__ A, const unsigned short* __restrict__ BT,
    const float* __restrict__ bias, void* __restrict__ Cv,
    int M, int K, int N) {
  constexpr int TR = BM / 32;
  constexpr int TC = BN / 32;
  __shared__ unsigned short As[BM * 32];
  __shared__ unsigned short Bs[BN * 32];
  const int t = threadIdx.x;
  const int wave = t >> 6, lane = t & 63;
  const int wr = wave >> 1, wc = wave & 1;
  const int bm = blockIdx.x * BM, bn = blockIdx.y * BN;

  f32x4 acc[TR][TC] = {};

  const int fr = lane & 15, q4 = lane >> 4;
  const int kBlocks = K >> 5;
  for (int kb = 0; kb < kBlocks; ++kb) {
    const int k0 = kb << 5;
    __syncthreads();
#pragma unroll
    for (int c = 0; c < BM * 4 / 256; ++c) {
      const int p = c * 256 + t;
      const int row = p >> 2;
      const int jl = (p & 3) ^ ((row >> 1) & 3);
      gl_lds16(A + (size_t)(bm + row) * K + k0 + jl * 8,
               As + (size_t)(c * 256 + wave * 64) * 8);
    }
#pragma unroll
    for (int c = 0; c < BN * 4 / 256; ++c) {
      const int p = c * 256 + t;
      const int row = p >> 2;
      const int jl = (p & 3) ^ ((row >> 1) & 3);
      gl_lds16(BT + (size_t)(bn + row) * K + k0 + jl * 8,
               Bs + (size_t)(c * 256 + wave * 64) * 8);
    }
    __syncthreads();
    s16x8 af[TR], bfr[TC];
#pragma unroll
    for (int i = 0; i < TR; ++i) {
      const int row = wr * (BM / 2) + i * 16 + fr;
      const int jp = q4 ^ ((row >> 1) & 3);
      af[i] = *(const s16x8*)(As + row * 32 + jp * 8);
    }
#pragma unroll
    for (int j = 0; j < TC; ++j) {
      const int row = wc * (BN / 2) + j * 16 + fr;
      const int jp = q4 ^ ((row >> 1) & 3);
      bfr[j] = *(const s16x8*)(Bs + row * 32 + jp * 8);
    }
#pragma unroll
    for (int i = 0; i < TR; ++i)
#pragma unroll
      for (int j = 0; j < TC; ++j)
        acc[i][j] = __builtin_amdgcn_mfma_f32_16x16x32_bf16(af[i], bfr[j],
                                                            acc[i][j], 0, 0, 0);
  }
#pragma unroll
  for (int i = 0; i < TR; ++i) {
#pragma unroll
    for (int j = 0; j < TC; ++j) {
      const int col = bn + wc * (BN / 2) + j * 16 + fr;
      const float bv = BIAS ? bias[col] : 0.0f;
#pragma unroll
      for (int r = 0; r < 4; ++r) {
        const int row = bm + wr * (BM / 2) + i * 16 + q4 * 4 + r;
        if constexpr (OUTBF) {
          ((unsigned short*)Cv)[(size_t)row * N + col] = f2bf(acc[i][j][r] + bv);
        } else {
          ((float*)Cv)[(size_t)row * N + col] = acc[i][j][r] + bv;
        }
      }
    }
  }
}

// ---------------- K3: fused QK^T -> softmax -> AV (MFMA), per (b,h,ntile) ----
#define PSTR 264
#define KSTR 72
__global__ __launch_bounds__(256) void fused_attn_kernel(
    const unsigned short* __restrict__ qkvb, unsigned short* __restrict__ attnb,
    unsigned short* __restrict__ oav) {
  __shared__ unsigned short kv_lds[256 * KSTR];
  __shared__ unsigned short p_lds[64 * PSTR];
  const int bh = blockIdx.y, b = bh >> 3, h = bh & 7;
  const int n0 = blockIdx.x * 64;
  const int t = threadIdx.x, wave = t >> 6, lane = t & 63;
  const int fr = lane & 15, q4 = lane >> 4;

  {
    const int dc = (t & 7) * 8;
#pragma unroll
    for (int p = 0; p < 8; ++p) {
      const int m = p * 32 + (t >> 3);
      const s16x8 v =
          *(const s16x8*)(qkvb + (size_t)(b * SEQ + m) * 1536 + 512 + h * 64 + dc);
      *(s16x8*)(kv_lds + m * KSTR + dc) = v;
    }
  }
  s16x8 qf[2];
  {
    const size_t qrow = (size_t)(b * SEQ + n0 + wave * 16 + fr) * 1536 + h * 64;
#pragma unroll
    for (int ks = 0; ks < 2; ++ks)
      qf[ks] = *(const s16x8*)(qkvb + qrow + ks * 32 + q4 * 8);
  }
  __syncthreads();

  f32x4 s[16];
#pragma unroll
  for (int mt = 0; mt < 16; ++mt) s[mt] = (f32x4){0.f, 0.f, 0.f, 0.f};
#pragma unroll
  for (int ks = 0; ks < 2; ++ks)
#pragma unroll
    for (int mt = 0; mt < 16; ++mt) {
      const s16x8 kf =
          *(const s16x8*)(kv_lds + (mt * 16 + fr) * KSTR + ks * 32 + q4 * 8);
      s[mt] = __builtin_amdgcn_mfma_f32_16x16x32_bf16(qf[ks], kf, s[mt], 0, 0, 0);
    }

  float mx[4] = {-1e30f, -1e30f, -1e30f, -1e30f};
#pragma unroll
  for (int mt = 0; mt < 16; ++mt)
#pragma unroll
    for (int r = 0; r < 4; ++r) {
      s[mt][r] *= SCALEF;
      mx[r] = fmaxf(mx[r], s[mt][r]);
    }
#pragma unroll
  for (int r = 0; r < 4; ++r) {
    mx[r] = fmaxf(mx[r], __shfl_xor(mx[r], 1));
    mx[r] = fmaxf(mx[r], __shfl_xor(mx[r], 2));
    mx[r] = fmaxf(mx[r], __shfl_xor(mx[r], 4));
    mx[r] = fmaxf(mx[r], __shfl_xor(mx[r], 8));
  }
  float sum[4] = {0.f, 0.f, 0.f, 0.f};
#pragma unroll
  for (int mt = 0; mt < 16; ++mt)
#pragma unroll
    for (int r = 0; r < 4; ++r) {
      s[mt][r] = __expf(s[mt][r] - mx[r]);
      sum[r] += s[mt][r];
    }
#pragma unroll
  for (int r = 0; r < 4; ++r) {
    sum[r] += __shfl_xor(sum[r], 1);
    sum[r] += __shfl_xor(sum[r], 2);
    sum[r] += __shfl_xor(sum[r], 4);
    sum[r] += __shfl_xor(sum[r], 8);
  }
  const float invs[4] = {1.0f / sum[0], 1.0f / sum[1], 1.0f / sum[2],
                         1.0f / sum[3]};

  __syncthreads();

  {
    const int nb = wave * 16 + q4 * 4;
#pragma unroll
    for (int mt = 0; mt < 16; ++mt)
#pragma unroll
      for (int r = 0; r < 4; ++r)
        p_lds[(nb + r) * PSTR + mt * 16 + fr] = f2bf(s[mt][r] * invs[r]);
  }
  {
    const int dc = (t & 7) * 8;
#pragma unroll
    for (int p = 0; p < 8; ++p) {
      const int m = p * 32 + (t >> 3);
      const s16x8 v =
          *(const s16x8*)(qkvb + (size_t)(b * SEQ + m) * 1536 + 1024 + h * 64 + dc);
#pragma unroll
      for (int j = 0; j < 8; ++j) kv_lds[(dc + j) * PSTR + m] = v[j];
    }
  }
  __syncthreads();

#pragma unroll
  for (int p = 0; p < 8; ++p) {
    const int idx = p * 256 + t;
    const int row = idx >> 5, mc = (idx & 31) * 8;
    *(s16x8*)(attnb + (size_t)(bh * SEQ + n0 + row) * SEQ + mc) =
        *(const s16x8*)(p_lds + row * PSTR + mc);
  }

  f32x4 o[4];
#pragma unroll
  for (int dt = 0; dt < 4; ++dt) o[dt] = (f32x4){0.f, 0.f, 0.f, 0.f};
#pragma unroll
  for (int ks = 0; ks < 8; ++ks) {
    const s16x8 pf =
        *(const s16x8*)(p_lds + (wave * 16 + fr) * PSTR + ks * 32 + q4 * 8);
#pragma unroll
    for (int dt = 0; dt < 4; ++dt) {
      const s16x8 vf =
          *(const s16x8*)(kv_lds + (dt * 16 + fr) * PSTR + ks * 32 + q4 * 8);
      o[dt] = __builtin_amdgcn_mfma_f32_16x16x32_bf16(pf, vf, o[dt], 0, 0, 0);
    }
  }
#pragma unroll
  for (int dt = 0; dt < 4; ++dt)
#pragma unroll
    for (int r = 0; r < 4; ++r) {
      const int n = n0 + wave * 16 + q4 * 4 + r;
      oav[(size_t)(b * SEQ + n) * DIMC + h * 64 + dt * 16 + fr] = f2bf(o[dt][r]);
    }
}

// ---------------- K4: rpos gather (bf16 up) + o_av add -> ob (bf16) ----------
#define RSTRIDE 280
__global__ __launch_bounds__(256) void rpos_kernel(
    const unsigned short* __restrict__ attnb, const unsigned short* __restrict__ upb,
    unsigned short* __restrict__ ob) {
  __shared__ float aS[4][8 * RSTRIDE];
  const int t = threadIdx.x;
  const int wave = t >> 6, lane = t & 63;
  const int g = lane >> 4, dg = lane & 15;
  const int pair = blockIdx.x * 4 + wave;
  const int n = pair >> 3, h = pair & 7;
  float* aW = aS[wave];

  const int m4 = lane * 4;
  const int sm4 = m4 + ((m4 >> 6) << 3);
#pragma unroll
  for (int b = 0; b < 8; ++b) {
    const ushort4 v =
        *(const ushort4*)&attnb[(size_t)((b * 8 + h) * SEQ + n) * SEQ + m4];
    float4 f;
    f.x = bf2f(v.x); f.y = bf2f(v.y); f.z = bf2f(v.z); f.w = bf2f(v.w);
    *(float4*)&aW[b * RSTRIDE + sm4] = f;
  }
  __syncthreads();

  const int xn = n >> 4, yn = n & 15;
  float acc[8][4];
#pragma unroll
  for (int b = 0; b < 8; ++b)
#pragma unroll
    for (int j = 0; j < 4; ++j) acc[b][j] = 0.0f;

  const int mbase = g * 64;
  const int sbase = g * 72;
#pragma unroll 4
  for (int mm = 0; mm < 64; ++mm) {
    const int m = mbase + mm;
    const int xm = m >> 4, ym = m & 15;
    const int row = (xn - xm + 15) * 31 + (yn - ym + 15);
    const ushort4 uu = *(const ushort4*)&upb[(size_t)row * DIMC + h * 64 + dg * 4];
    const float ux = bf2f(uu.x), uy = bf2f(uu.y), uz = bf2f(uu.z), uw = bf2f(uu.w);
    float ab[8];
#pragma unroll
    for (int b = 0; b < 8; ++b) ab[b] = aW[b * RSTRIDE + sbase + mm];
#pragma unroll
    for (int b = 0; b < 8; ++b) {
      acc[b][0] += ab[b] * ux;
      acc[b][1] += ab[b] * uy;
      acc[b][2] += ab[b] * uz;
      acc[b][3] += ab[b] * uw;
    }
  }
#pragma unroll
  for (int b = 0; b < 8; ++b)
#pragma unroll
    for (int j = 0; j < 4; ++j) {
      float v = acc[b][j];
      v += __shfl_xor(v, 16);
      v += __shfl_xor(v, 32);
      acc[b][j] = v;
    }
#pragma unroll
  for (int k = 0; k < 2; ++k) {
    const int b = g * 2 + k;
    const size_t base = (size_t)(b * SEQ + n) * DIMC + h * 64 + dg * 4;
    ushort4 pv = *(ushort4*)&ob[base];
    ushort4 w;
    w.x = f2bf(bf2f(pv.x) + acc[b][0]);
    w.y = f2bf(bf2f(pv.y) + acc[b][1]);
    w.z = f2bf(bf2f(pv.z) + acc[b][2]);
    w.w = f2bf(bf2f(pv.w) + acc[b][3]);
    *(ushort4*)&ob[base] = w;
  }
}

extern "C" void kernel_launch(void* const* d_in, const int* in_sizes, int n_in,
                              void* d_out, int out_size, void* d_ws,
                              size_t ws_size, hipStream_t stream) {
  const float* x = (const float*)d_in[0];
  const float* ln_g = (const float*)d_in[1];
  const float* ln_b = (const float*)d_in[2];
  const float* w_qkv = (const float*)d_in[3];
  const float* up = (const float*)d_in[4];
  const float* w_out = (const float*)d_in[5];
  const float* b_out = (const float*)d_in[6];
  float* out = (float*)d_out;

  unsigned short* u = (unsigned short*)d_ws;
  unsigned short* qkvb = u;                  // 3,145,728
  unsigned short* attnb = u + 3145728;       // 4,194,304
  unsigned short* xnb = u + 7340032;         // 1,048,576
  unsigned short* ob = u + 8388608;          // 1,048,576
  unsigned short* wqt = u + 9437184;         //   786,432
  unsigned short* wot = u + 10223616;        //   262,144
  unsigned short* upb = u + 10485760;        //   492,032
  if (ws_size < (size_t)10977792 * sizeof(unsigned short)) return;  // ~22 MB

  prep_kernel<<<2545, 256, 0, stream>>>(x, ln_g, ln_b, w_qkv, w_out, up,
                                        xnb, wqt, wot, upb);
  mfma_gemm_bt<128, 128, false, true>
      <<<dim3(16, 12), 256, 0, stream>>>(xnb, wqt, nullptr, qkvb, 2048, 512, 1536);
  fused_attn_kernel<<<dim3(4, 64), 256, 0, stream>>>(qkvb, attnb, ob);
  rpos_kernel<<<512, 256, 0, stream>>>(attnb, upb, ob);
  mfma_gemm_bt<64, 64, true, false>
      <<<dim3(32, 8), 256, 0, stream>>>(ob, wot, b_out, out, 2048, 512, 512);
}

// Round 8
// 120.341 us; speedup vs baseline: 4.9018x; 1.0238x over previous
//
#include <hip/hip_runtime.h>
#include <math.h>

#define NB 8
#define SEQ 256
#define DIMC 512
#define NHEAD 8
#define DHEAD 64
#define SCALEF 0.125f

typedef __attribute__((ext_vector_type(8))) short s16x8;
typedef __attribute__((ext_vector_type(4))) float f32x4;

typedef __attribute__((address_space(3))) unsigned int lds_u32_t;
typedef const __attribute__((address_space(1))) unsigned int g_u32_t;
static __device__ __forceinline__ void gl_lds16(const void* gsrc, void* ldst) {
  __builtin_amdgcn_global_load_lds((g_u32_t*)gsrc, (lds_u32_t*)ldst, 16, 0, 0);
}

static __device__ __forceinline__ unsigned short f2bf(float f) {
  union { float f; unsigned u; } c; c.f = f;
  unsigned r = c.u + 0x7FFF + ((c.u >> 16) & 1);  // RNE
  return (unsigned short)(r >> 16);
}
static __device__ __forceinline__ float bf2f(unsigned short u) {
  union { unsigned u; float f; } c; c.u = ((unsigned)u) << 16;
  return c.f;
}

// ---------------- K0: fused prep: tcast(w_qkv), tcast(w_out), up->bf16, LN ---
static __device__ void tcast_body(const float* __restrict__ W,
    unsigned short* __restrict__ WT, int K, int N, int n0, int k0, int t,
    float (*tile)[65]) {
#pragma unroll
  for (int i = 0; i < 16; ++i) {
    const int idx = i * 256 + t;
    const int kl = idx >> 6, nl = idx & 63;
    tile[kl][nl] = W[(size_t)(k0 + kl) * N + n0 + nl];
  }
  __syncthreads();
#pragma unroll
  for (int i = 0; i < 16; ++i) {
    const int idx = i * 256 + t;
    const int nl = idx >> 6, kl = idx & 63;
    WT[(size_t)(n0 + nl) * K + k0 + kl] = f2bf(tile[kl][nl]);
  }
}

__global__ __launch_bounds__(256) void prep_kernel(const float* __restrict__ x,
    const float* __restrict__ g, const float* __restrict__ bta,
    const float* __restrict__ w_qkv, const float* __restrict__ w_out,
    const float* __restrict__ up, unsigned short* __restrict__ xnb,
    unsigned short* __restrict__ wqt, unsigned short* __restrict__ wot,
    unsigned short* __restrict__ upb) {
  __shared__ float tile[64][65];
  __shared__ float sh_s[4], sh_q[4];
  const int t = threadIdx.x;
  const int bid = blockIdx.x;
  if (bid < 192) {
    tcast_body(w_qkv, wqt, 512, 1536, (bid % 24) * 64, (bid / 24) * 64, t, tile);
  } else if (bid < 256) {
    const int b2 = bid - 192;
    tcast_body(w_out, wot, 512, 512, (b2 % 8) * 64, (b2 / 8) * 64, t, tile);
  } else if (bid < 497) {
    const int base = (bid - 256) * 2048 + t * 4;
#pragma unroll
    for (int it = 0; it < 2; ++it) {
      const int i = base + it * 1024;
      if (i < 492032) {
        const float4 v = *(const float4*)&up[i];
        ushort4 w;
        w.x = f2bf(v.x); w.y = f2bf(v.y); w.z = f2bf(v.z); w.w = f2bf(v.w);
        *(ushort4*)&upb[i] = w;
      }
    }
  } else {
    const int row = bid - 497;
    const float2 v = ((const float2*)(x + (size_t)row * DIMC))[t];
    float s = v.x + v.y;
    float q = v.x * v.x + v.y * v.y;
#pragma unroll
    for (int off = 32; off > 0; off >>= 1) {
      s += __shfl_down(s, off);
      q += __shfl_down(q, off);
    }
    const int wave = t >> 6, lane = t & 63;
    if (lane == 0) { sh_s[wave] = s; sh_q[wave] = q; }
    __syncthreads();
    const float fs = sh_s[0] + sh_s[1] + sh_s[2] + sh_s[3];
    const float fq = sh_q[0] + sh_q[1] + sh_q[2] + sh_q[3];
    const float mean = fs * (1.0f / DIMC);
    const float inv = rsqrtf(fq * (1.0f / DIMC) - mean * mean + 1e-5f);
    const float2 gv = ((const float2*)g)[t];
    const float2 bv = ((const float2*)bta)[t];
    ushort2 o;
    o.x = f2bf((v.x - mean) * inv * gv.x + bv.x);
    o.y = f2bf((v.y - mean) * inv * gv.y + bv.y);
    ((ushort2*)(xnb + (size_t)row * DIMC))[t] = o;
  }
}

// ---------------- bf16 MFMA GEMM: C = A(MxK) @ BT(NxK)^T (+bias) -------------
// VSPLIT (qkv only): output cols >=1024 (the V third) go transposed to
// vtb[(b*8+h)*64 + d][m] instead of row-major C (block-uniform branch).
template <int BM, int BN, bool BIAS, bool OUTBF, bool VSPLIT>
__global__ __launch_bounds__(256) void mfma_gemm_bt(
    const unsigned short* __restrict__ A, const unsigned short* __restrict__ BT,
    const float* __restrict__ bias, void* __restrict__ Cv,
    unsigned short* __restrict__ vtb, int M, int K, int N) {
  constexpr int TR = BM / 32;
  constexpr int TC = BN / 32;
  __shared__ unsigned short As[BM * 32];
  __shared__ unsigned short Bs[BN * 32];
  const int t = threadIdx.x;
  const int wave = t >> 6, lane = t & 63;
  const int wr = wave >> 1, wc = wave & 1;
  const int bm = blockIdx.x * BM, bn = blockIdx.y * BN;

  f32x4 acc[TR][TC] = {};

  const int fr = lane & 15, q4 = lane >> 4;
  const int kBlocks = K >> 5;
  for (int kb = 0; kb < kBlocks; ++kb) {
    const int k0 = kb << 5;
    __syncthreads();
#pragma unroll
    for (int c = 0; c < (BM * 4 + 255) / 256; ++c) {
      const int p = c * 256 + t;
      if (BM * 4 % 256 == 0 || p < BM * 4) {
        const int row = p >> 2;
        const int jl = (p & 3) ^ ((row >> 1) & 3);
        gl_lds16(A + (size_t)(bm + row) * K + k0 + jl * 8,
                 As + (size_t)(c * 256 + wave * 64) * 8);
      }
    }
#pragma unroll
    for (int c = 0; c < (BN * 4 + 255) / 256; ++c) {
      const int p = c * 256 + t;
      if (BN * 4 % 256 == 0 || p < BN * 4) {
        const int row = p >> 2;
        const int jl = (p & 3) ^ ((row >> 1) & 3);
        gl_lds16(BT + (size_t)(bn + row) * K + k0 + jl * 8,
                 Bs + (size_t)(c * 256 + wave * 64) * 8);
      }
    }
    __syncthreads();
    s16x8 af[TR], bfr[TC];
#pragma unroll
    for (int i = 0; i < TR; ++i) {
      const int row = wr * (BM / 2) + i * 16 + fr;
      const int jp = q4 ^ ((row >> 1) & 3);
      af[i] = *(const s16x8*)(As + row * 32 + jp * 8);
    }
#pragma unroll
    for (int j = 0; j < TC; ++j) {
      const int row = wc * (BN / 2) + j * 16 + fr;
      const int jp = q4 ^ ((row >> 1) & 3);
      bfr[j] = *(const s16x8*)(Bs + row * 32 + jp * 8);
    }
#pragma unroll
    for (int i = 0; i < TR; ++i)
#pragma unroll
      for (int j = 0; j < TC; ++j)
        acc[i][j] = __builtin_amdgcn_mfma_f32_16x16x32_bf16(af[i], bfr[j],
                                                            acc[i][j], 0, 0, 0);
  }
  if (VSPLIT && bn >= 1024) {
#pragma unroll
    for (int i = 0; i < TR; ++i) {
#pragma unroll
      for (int j = 0; j < TC; ++j) {
        const int hc = bn - 1024 + wc * (BN / 2) + j * 16 + fr;
        const int h = hc >> 6, d = hc & 63;
#pragma unroll
        for (int r = 0; r < 4; ++r) {
          const int row = bm + wr * (BM / 2) + i * 16 + q4 * 4 + r;
          const int b = row >> 8, m = row & 255;
          vtb[(size_t)((b * 8 + h) * 64 + d) * 256 + m] = f2bf(acc[i][j][r]);
        }
      }
    }
    return;
  }
#pragma unroll
  for (int i = 0; i < TR; ++i) {
#pragma unroll
    for (int j = 0; j < TC; ++j) {
      const int col = bn + wc * (BN / 2) + j * 16 + fr;
      const float bv = BIAS ? bias[col] : 0.0f;
#pragma unroll
      for (int r = 0; r < 4; ++r) {
        const int row = bm + wr * (BM / 2) + i * 16 + q4 * 4 + r;
        if constexpr (OUTBF) {
          ((unsigned short*)Cv)[(size_t)row * N + col] = f2bf(acc[i][j][r] + bv);
        } else {
          ((float*)Cv)[(size_t)row * N + col] = acc[i][j][r] + bv;
        }
      }
    }
  }
}

// ---------------- K3: fused QK^T -> softmax -> AV, 128 thr / 32 n-rows -------
// grid (8 ntiles, 64 bh). V^T comes pre-transposed from the qkv GEMM (vtb).
#define PSTR 264
#define KSTR 72
__global__ __launch_bounds__(128) void fused_attn_kernel(
    const unsigned short* __restrict__ qkvb, const unsigned short* __restrict__ vtb,
    unsigned short* __restrict__ attnb, unsigned short* __restrict__ oav) {
  __shared__ unsigned short kv_lds[256 * KSTR];  // K stage, then V^T stage
  __shared__ unsigned short p_lds[32 * PSTR];
  const int bh = blockIdx.y, b = bh >> 3, h = bh & 7;
  const int n0 = blockIdx.x * 32;
  const int t = threadIdx.x, wave = t >> 6, lane = t & 63;
  const int fr = lane & 15, q4 = lane >> 4;

  // stage K[m][d]: 256 rows x 8 chunks of 16B = 2048 chunks / 128 thr
#pragma unroll
  for (int p = 0; p < 16; ++p) {
    const int chunk = p * 128 + t;
    const int m = chunk >> 3, c = chunk & 7;
    *(s16x8*)(kv_lds + m * KSTR + c * 8) =
        *(const s16x8*)(qkvb + (size_t)(b * SEQ + m) * 1536 + 512 + h * 64 + c * 8);
  }
  s16x8 qf[2];
  {
    const size_t qrow = (size_t)(b * SEQ + n0 + wave * 16 + fr) * 1536 + h * 64;
#pragma unroll
    for (int ks = 0; ks < 2; ++ks)
      qf[ks] = *(const s16x8*)(qkvb + qrow + ks * 32 + q4 * 8);
  }
  __syncthreads();

  f32x4 s[16];
#pragma unroll
  for (int mt = 0; mt < 16; ++mt) s[mt] = (f32x4){0.f, 0.f, 0.f, 0.f};
#pragma unroll
  for (int ks = 0; ks < 2; ++ks)
#pragma unroll
    for (int mt = 0; mt < 16; ++mt) {
      const s16x8 kf =
          *(const s16x8*)(kv_lds + (mt * 16 + fr) * KSTR + ks * 32 + q4 * 8);
      s[mt] = __builtin_amdgcn_mfma_f32_16x16x32_bf16(qf[ks], kf, s[mt], 0, 0, 0);
    }

  float mx[4] = {-1e30f, -1e30f, -1e30f, -1e30f};
#pragma unroll
  for (int mt = 0; mt < 16; ++mt)
#pragma unroll
    for (int r = 0; r < 4; ++r) {
      s[mt][r] *= SCALEF;
      mx[r] = fmaxf(mx[r], s[mt][r]);
    }
#pragma unroll
  for (int r = 0; r < 4; ++r) {
    mx[r] = fmaxf(mx[r], __shfl_xor(mx[r], 1));
    mx[r] = fmaxf(mx[r], __shfl_xor(mx[r], 2));
    mx[r] = fmaxf(mx[r], __shfl_xor(mx[r], 4));
    mx[r] = fmaxf(mx[r], __shfl_xor(mx[r], 8));
  }
  float sum[4] = {0.f, 0.f, 0.f, 0.f};
#pragma unroll
  for (int mt = 0; mt < 16; ++mt)
#pragma unroll
    for (int r = 0; r < 4; ++r) {
      s[mt][r] = __expf(s[mt][r] - mx[r]);
      sum[r] += s[mt][r];
    }
#pragma unroll
  for (int r = 0; r < 4; ++r) {
    sum[r] += __shfl_xor(sum[r], 1);
    sum[r] += __shfl_xor(sum[r], 2);
    sum[r] += __shfl_xor(sum[r], 4);
    sum[r] += __shfl_xor(sum[r], 8);
  }
  const float invs[4] = {1.0f / sum[0], 1.0f / sum[1], 1.0f / sum[2],
                         1.0f / sum[3]};

  __syncthreads();  // waves done with K before V^T overwrites kv_lds

  // P -> p_lds (bf16), V^T -> kv_lds (vector b128, 2048 chunks / 128 thr)
  {
    const int nb = wave * 16 + q4 * 4;
#pragma unroll
    for (int mt = 0; mt < 16; ++mt)
#pragma unroll
      for (int r = 0; r < 4; ++r)
        p_lds[(nb + r) * PSTR + mt * 16 + fr] = f2bf(s[mt][r] * invs[r]);
  }
#pragma unroll
  for (int p = 0; p < 16; ++p) {
    const int idx = p * 128 + t;
    const int d = idx >> 5, c = idx & 31;
    *(s16x8*)(kv_lds + d * PSTR + c * 8) =
        *(const s16x8*)(vtb + (size_t)(bh * 64 + d) * 256 + c * 8);
  }
  __syncthreads();

  // copy P -> global attn (bf16) for the rpos kernel
#pragma unroll
  for (int p = 0; p < 8; ++p) {
    const int idx = p * 128 + t;
    const int row = idx >> 5, mc = (idx & 31) * 8;
    *(s16x8*)(attnb + (size_t)(bh * SEQ + n0 + row) * SEQ + mc) =
        *(const s16x8*)(p_lds + row * PSTR + mc);
  }

  f32x4 o[4];
#pragma unroll
  for (int dt = 0; dt < 4; ++dt) o[dt] = (f32x4){0.f, 0.f, 0.f, 0.f};
#pragma unroll
  for (int ks = 0; ks < 8; ++ks) {
    const s16x8 pf =
        *(const s16x8*)(p_lds + (wave * 16 + fr) * PSTR + ks * 32 + q4 * 8);
#pragma unroll
    for (int dt = 0; dt < 4; ++dt) {
      const s16x8 vf =
          *(const s16x8*)(kv_lds + (dt * 16 + fr) * PSTR + ks * 32 + q4 * 8);
      o[dt] = __builtin_amdgcn_mfma_f32_16x16x32_bf16(pf, vf, o[dt], 0, 0, 0);
    }
  }
#pragma unroll
  for (int dt = 0; dt < 4; ++dt)
#pragma unroll
    for (int r = 0; r < 4; ++r) {
      const int n = n0 + wave * 16 + q4 * 4 + r;
      oav[(size_t)(b * SEQ + n) * DIMC + h * 64 + dt * 16 + fr] = f2bf(o[dt][r]);
    }
}

// ---------------- K4: rpos gather + o_av add, wave per (n,h,bhalf) -----------
#define RSTRIDE 280
__global__ __launch_bounds__(256) void rpos_kernel(
    const unsigned short* __restrict__ attnb, const unsigned short* __restrict__ upb,
    unsigned short* __restrict__ ob) {
  __shared__ float aS[4][4 * RSTRIDE];
  const int t = threadIdx.x;
  const int wave = t >> 6, lane = t & 63;
  const int g = lane >> 4, dg = lane & 15;
  const int idx = blockIdx.x * 4 + wave;   // 4096 pairs
  const int bhalf = idx & 1;
  const int h = (idx >> 1) & 7;
  const int n = idx >> 4;
  float* aW = aS[wave];

  const int m4 = lane * 4;
  const int sm4 = m4 + ((m4 >> 6) << 3);
#pragma unroll
  for (int bl = 0; bl < 4; ++bl) {
    const int b = bhalf * 4 + bl;
    const ushort4 v =
        *(const ushort4*)&attnb[(size_t)((b * 8 + h) * SEQ + n) * SEQ + m4];
    float4 f;
    f.x = bf2f(v.x); f.y = bf2f(v.y); f.z = bf2f(v.z); f.w = bf2f(v.w);
    *(float4*)&aW[bl * RSTRIDE + sm4] = f;
  }
  __syncthreads();

  const int xn = n >> 4, yn = n & 15;
  float acc[4][4];
#pragma unroll
  for (int bl = 0; bl < 4; ++bl)
#pragma unroll
    for (int j = 0; j < 4; ++j) acc[bl][j] = 0.0f;

  const int mbase = g * 64;
  const int sbase = g * 72;
#pragma unroll 4
  for (int mm = 0; mm < 64; ++mm) {
    const int m = mbase + mm;
    const int xm = m >> 4, ym = m & 15;
    const int row = (xn - xm + 15) * 31 + (yn - ym + 15);
    const ushort4 uu = *(const ushort4*)&upb[(size_t)row * DIMC + h * 64 + dg * 4];
    const float ux = bf2f(uu.x), uy = bf2f(uu.y), uz = bf2f(uu.z), uw = bf2f(uu.w);
    float ab[4];
#pragma unroll
    for (int bl = 0; bl < 4; ++bl) ab[bl] = aW[bl * RSTRIDE + sbase + mm];
#pragma unroll
    for (int bl = 0; bl < 4; ++bl) {
      acc[bl][0] += ab[bl] * ux;
      acc[bl][1] += ab[bl] * uy;
      acc[bl][2] += ab[bl] * uz;
      acc[bl][3] += ab[bl] * uw;
    }
  }
#pragma unroll
  for (int bl = 0; bl < 4; ++bl)
#pragma unroll
    for (int j = 0; j < 4; ++j) {
      float v = acc[bl][j];
      v += __shfl_xor(v, 16);
      v += __shfl_xor(v, 32);
      acc[bl][j] = v;
    }
  {
    const int b = bhalf * 4 + g;
    const size_t base = (size_t)(b * SEQ + n) * DIMC + h * 64 + dg * 4;
    ushort4 pv = *(ushort4*)&ob[base];
    ushort4 w;
    w.x = f2bf(bf2f(pv.x) + acc[g][0]);
    w.y = f2bf(bf2f(pv.y) + acc[g][1]);
    w.z = f2bf(bf2f(pv.z) + acc[g][2]);
    w.w = f2bf(bf2f(pv.w) + acc[g][3]);
    *(ushort4*)&ob[base] = w;
  }
}

extern "C" void kernel_launch(void* const* d_in, const int* in_sizes, int n_in,
                              void* d_out, int out_size, void* d_ws,
                              size_t ws_size, hipStream_t stream) {
  const float* x = (const float*)d_in[0];
  const float* ln_g = (const float*)d_in[1];
  const float* ln_b = (const float*)d_in[2];
  const float* w_qkv = (const float*)d_in[3];
  const float* up = (const float*)d_in[4];
  const float* w_out = (const float*)d_in[5];
  const float* b_out = (const float*)d_in[6];
  float* out = (float*)d_out;

  unsigned short* u = (unsigned short*)d_ws;
  unsigned short* qkvb = u;                  // 3,145,728 (V third unused)
  unsigned short* attnb = u + 3145728;       // 4,194,304
  unsigned short* xnb = u + 7340032;         // 1,048,576
  unsigned short* ob = u + 8388608;          // 1,048,576
  unsigned short* wqt = u + 9437184;         //   786,432
  unsigned short* wot = u + 10223616;        //   262,144
  unsigned short* upb = u + 10485760;        //   492,032
  unsigned short* vtb = u + 10977792;        // 1,048,576
  if (ws_size < (size_t)12026368 * sizeof(unsigned short)) return;  // ~24 MB

  prep_kernel<<<2545, 256, 0, stream>>>(x, ln_g, ln_b, w_qkv, w_out, up,
                                        xnb, wqt, wot, upb);
  mfma_gemm_bt<64, 64, false, true, true>
      <<<dim3(32, 24), 256, 0, stream>>>(xnb, wqt, nullptr, qkvb, vtb,
                                         2048, 512, 1536);
  fused_attn_kernel<<<dim3(8, 64), 128, 0, stream>>>(qkvb, vtb, attnb, ob);
  rpos_kernel<<<1024, 256, 0, stream>>>(attnb, upb, ob);
  mfma_gemm_bt<64, 32, true, false, false>
      <<<dim3(32, 16), 256, 0, stream>>>(ob, wot, b_out, out, nullptr,
                                         2048, 512, 512);
}